// Round 2
// baseline (1015.268 us; speedup 1.0000x reference)
//
#include <hip/hip_runtime.h>
#include <math.h>

#define NB 4
#define CC 256
#define CO 32
#define NN 4096

typedef __attribute__((ext_vector_type(4))) float f4;

// ---------------------------------------------------------------------------
// Kernel 1: projections. q[b][n][o] (o<32), kT[b][n][o] (o<32), v[b][n][c].
// Unified output index u in [0,320): u<32 -> q, u<64 -> k, else v.
// grid = b(4) x nblk(16) x ublk(5); block = 256.
// Thread: 16 consecutive u, 4 consecutive n (float4 along n, coalesced x reads).
// ---------------------------------------------------------------------------
__global__ __launch_bounds__(256) void proj_kernel(
    const float* __restrict__ x,
    const float* __restrict__ Wq, const float* __restrict__ bq,
    const float* __restrict__ Wk, const float* __restrict__ bk,
    const float* __restrict__ Wv, const float* __restrict__ bv,
    float* __restrict__ q, float* __restrict__ kT, float* __restrict__ v)
{
    const int t    = threadIdx.x;
    const int blk  = blockIdx.x;
    const int ublk = blk % 5;
    const int nblk = (blk / 5) % 16;
    const int b    = blk / 80;
    const int lane = t & 63;
    const int g    = t >> 6;                 // wave id (uniform per wave)
    const int u0   = ublk * 64 + g * 16;     // 16 consecutive outputs
    const int n4   = nblk * 256 + lane * 4;  // 4 consecutive positions

    const float* wbase;
    const float* bias;
    if (u0 < 32)      { wbase = Wq + (size_t)u0 * CC;        bias = bq + u0; }
    else if (u0 < 64) { wbase = Wk + (size_t)(u0 - 32) * CC; bias = bk + (u0 - 32); }
    else              { wbase = Wv + (size_t)(u0 - 64) * CC; bias = bv + (u0 - 64); }

    float acc[16][4];
    #pragma unroll
    for (int u = 0; u < 16; ++u) {
        float bb = bias[u];
        #pragma unroll
        for (int j = 0; j < 4; ++j) acc[u][j] = bb;
    }

    for (int c = 0; c < CC; c += 4) {
        f4 xv[4];
        #pragma unroll
        for (int cc = 0; cc < 4; ++cc)
            xv[cc] = *reinterpret_cast<const f4*>(x + ((size_t)(b * CC + c + cc)) * NN + n4);
        #pragma unroll
        for (int u = 0; u < 16; ++u) {
            f4 wv = *reinterpret_cast<const f4*>(wbase + (size_t)u * CC + c);
            #pragma unroll
            for (int cc = 0; cc < 4; ++cc) {
                #pragma unroll
                for (int j = 0; j < 4; ++j)
                    acc[u][j] += wv[cc] * xv[cc][j];
            }
        }
    }

    float* dst; int o0; int rs;
    if (u0 < 32)      { dst = q;  o0 = u0;      rs = 32; }
    else if (u0 < 64) { dst = kT; o0 = u0 - 32; rs = 32; }
    else              { dst = v;  o0 = u0 - 64; rs = 256; }

    #pragma unroll
    for (int j = 0; j < 4; ++j) {
        const int n = n4 + j;
        float* p = dst + ((size_t)(b * NN + n)) * rs + o0;
        #pragma unroll
        for (int uu = 0; uu < 16; uu += 4) {
            f4 st = { acc[uu][j], acc[uu + 1][j], acc[uu + 2][j], acc[uu + 3][j] };
            *reinterpret_cast<f4*>(p + uu) = st;
        }
    }
}

// ---------------------------------------------------------------------------
// Kernel 2: column stats. softmax is over n (axis=1): for each column m,
// cmax[m] = max_n S[n,m]; cinv[m] = 1 / sum_n exp(S[n,m]-cmax[m]).
// grid = b(4) x mblk(64) (64 columns per block); block = 256 (4 waves/col set).
// k column held in regs; q tiles staged in LDS (broadcast reads per wave).
// ---------------------------------------------------------------------------
__global__ __launch_bounds__(256) void colstats_kernel(
    const float* __restrict__ q, const float* __restrict__ kT,
    float* __restrict__ cmax, float* __restrict__ cinv)
{
    __shared__ float qlds[128 * 32];
    __shared__ float redm[4][64];
    __shared__ float reds[4][64];

    const int t    = threadIdx.x;
    const int b    = blockIdx.x >> 6;
    const int mblk = blockIdx.x & 63;
    const int ml   = t & 63;                  // column within tile
    const int g    = t >> 6;                  // wave id: n-subset
    const int m    = mblk * 64 + ml;

    f4 kreg[8];
    {
        const f4* kp = reinterpret_cast<const f4*>(kT + ((size_t)(b * NN + m)) * CO);
        #pragma unroll
        for (int i = 0; i < 8; ++i) kreg[i] = kp[i];
    }

    float mx = -1e30f, sm = 0.f;

    for (int n0 = 0; n0 < NN; n0 += 128) {
        __syncthreads();
        const float* qg = q + ((size_t)(b * NN + n0)) * CO;
        for (int idx = t; idx < 128 * 32; idx += 256) qlds[idx] = qg[idx];
        __syncthreads();

        for (int i = 0; i < 32; ++i) {
            const int nl = g * 32 + i;
            const f4* qr = reinterpret_cast<const f4*>(qlds + nl * 32);
            float s = 0.f;
            #pragma unroll
            for (int o = 0; o < 8; ++o) {
                f4 qv = qr[o];
                s += qv[0] * kreg[o][0] + qv[1] * kreg[o][1]
                   + qv[2] * kreg[o][2] + qv[3] * kreg[o][3];
            }
            if (s > mx) { sm = sm * __expf(mx - s) + 1.f; mx = s; }
            else        { sm += __expf(s - mx); }
        }
    }

    redm[g][ml] = mx;
    reds[g][ml] = sm;
    __syncthreads();
    if (t < 64) {
        float M = redm[0][t];
        #pragma unroll
        for (int i = 1; i < 4; ++i) M = fmaxf(M, redm[i][t]);
        float S = 0.f;
        #pragma unroll
        for (int i = 0; i < 4; ++i) S += reds[i][t] * __expf(redm[i][t] - M);
        cmax[b * NN + mblk * 64 + t] = M;
        cinv[b * NN + mblk * 64 + t] = 1.0f / S;
    }
}

// ---------------------------------------------------------------------------
// Kernel 3: out[n,c] = sum_m exp(S[n,m]-cmax[m]) * (v[m,c]*cinv[m]).
// grid = b(4) x nblk(128) (32 rows per block); block = 256.
// Per m-tile(32): stage kT + scaled-v in LDS; phase1 S+exp -> plds (q rows in
// regs, k broadcast-b128); phase2 P@V' (p broadcast-b128, v dense-b128).
// ---------------------------------------------------------------------------
__global__ __launch_bounds__(256) void attn_kernel(
    const float* __restrict__ q, const float* __restrict__ kT,
    const float* __restrict__ v, const float* __restrict__ cmax,
    const float* __restrict__ cinv, float* __restrict__ out)
{
    __shared__ float klds[32 * 32];
    __shared__ float plds[32 * 36];    // pad to 36 (16B-aligned rows, bank-spread)
    __shared__ float vlds[32 * 256];

    const int t    = threadIdx.x;
    const int b    = blockIdx.x >> 7;
    const int nblk = blockIdx.x & 127;
    const int n0   = nblk * 32;
    const int lane = t & 63;
    const int wv   = t >> 6;          // wave id: owns rows wv*8..wv*8+7, cols lane*4..+3
    const int r1   = t & 31;          // phase-1 row
    const int mg   = t >> 5;          // phase-1 m-group (0..7)

    f4 qreg[8];
    {
        const f4* qp = reinterpret_cast<const f4*>(q + ((size_t)(b * NN + n0 + r1)) * CO);
        #pragma unroll
        for (int i = 0; i < 8; ++i) qreg[i] = qp[i];
    }

    f4 acc[8];
    #pragma unroll
    for (int k = 0; k < 8; ++k) acc[k] = (f4){0.f, 0.f, 0.f, 0.f};

    const float* cmax_b = cmax + b * NN;
    const float* cinv_b = cinv + b * NN;

    for (int m0 = 0; m0 < NN; m0 += 32) {
        __syncthreads();
        // stage kT tile (32x32): 1 f4 per thread
        {
            const int row = t >> 3, o4 = t & 7;
            f4 kv = *reinterpret_cast<const f4*>(kT + ((size_t)(b * NN + m0 + row)) * CO + o4 * 4);
            *reinterpret_cast<f4*>(klds + row * 32 + o4 * 4) = kv;
        }
        // stage v tile (32x256) scaled by cinv: 8 f4 per thread
        {
            #pragma unroll
            for (int i = 0; i < 8; ++i) {
                const int idx4 = t + i * 256;
                const int row  = idx4 >> 6;
                const int c4   = idx4 & 63;
                const float inv = cinv_b[m0 + row];
                f4 vv = *reinterpret_cast<const f4*>(v + ((size_t)(b * NN + m0 + row)) * CC + c4 * 4);
                vv *= inv;
                *reinterpret_cast<f4*>(vlds + row * 256 + c4 * 4) = vv;
            }
        }
        __syncthreads();
        // phase 1: S tile + exp -> plds
        #pragma unroll
        for (int j = 0; j < 4; ++j) {
            const int m = mg + 8 * j;
            const f4* kr = reinterpret_cast<const f4*>(klds + m * 32);
            float s = 0.f;
            #pragma unroll
            for (int o = 0; o < 8; ++o) {
                f4 kv = kr[o];
                s += qreg[o][0] * kv[0] + qreg[o][1] * kv[1]
                   + qreg[o][2] * kv[2] + qreg[o][3] * kv[3];
            }
            plds[r1 * 36 + m] = __expf(s - cmax_b[m0 + m]);
        }
        __syncthreads();
        // phase 2: acc += P(rows wv*8+k) @ V'
        #pragma unroll
        for (int m4 = 0; m4 < 8; ++m4) {
            f4 p4[8];
            #pragma unroll
            for (int k = 0; k < 8; ++k)
                p4[k] = *reinterpret_cast<const f4*>(plds + (wv * 8 + k) * 36 + m4 * 4);
            #pragma unroll
            for (int jj = 0; jj < 4; ++jj) {
                f4 vv = *reinterpret_cast<const f4*>(vlds + (m4 * 4 + jj) * 256 + lane * 4);
                #pragma unroll
                for (int k = 0; k < 8; ++k) {
                    acc[k][0] += p4[k][jj] * vv[0];
                    acc[k][1] += p4[k][jj] * vv[1];
                    acc[k][2] += p4[k][jj] * vv[2];
                    acc[k][3] += p4[k][jj] * vv[3];
                }
            }
        }
    }

    #pragma unroll
    for (int k = 0; k < 8; ++k) {
        const int n = n0 + wv * 8 + k;
        *reinterpret_cast<f4*>(out + ((size_t)(b * NN + n)) * CC + lane * 4) = acc[k];
    }
}

extern "C" void kernel_launch(void* const* d_in, const int* in_sizes, int n_in,
                              void* d_out, int out_size, void* d_ws, size_t ws_size,
                              hipStream_t stream)
{
    const float* x  = (const float*)d_in[0];
    const float* Wq = (const float*)d_in[1];
    const float* bq = (const float*)d_in[2];
    const float* Wk = (const float*)d_in[3];
    const float* bk = (const float*)d_in[4];
    const float* Wv = (const float*)d_in[5];
    const float* bv = (const float*)d_in[6];
    float* out = (float*)d_out;

    // workspace layout (floats): q | kT | v | cmax | cinv  (~20.2 MB total)
    float* ws = (float*)d_ws;
    float* q   = ws;                      // 4*4096*32  = 524288
    float* kT  = q  + (size_t)NB * NN * CO;
    float* v   = kT + (size_t)NB * NN * CO;   // 4*4096*256 = 4194304
    float* cm  = v  + (size_t)NB * NN * CC;
    float* ci  = cm + (size_t)NB * NN;

    proj_kernel<<<dim3(320), dim3(256), 0, stream>>>(x, Wq, bq, Wk, bk, Wv, bv, q, kT, v);
    colstats_kernel<<<dim3(256), dim3(256), 0, stream>>>(q, kT, cm, ci);
    attn_kernel<<<dim3(512), dim3(256), 0, stream>>>(q, kT, v, cm, ci, out);
}

// Round 3
// 277.559 us; speedup vs baseline: 3.6578x; 3.6578x over previous
//
#include <hip/hip_runtime.h>
#include <math.h>

#define NB 4
#define CC 256
#define CO 32
#define NN 4096

typedef __attribute__((ext_vector_type(4))) float f4;
typedef __attribute__((ext_vector_type(8))) short s8;          // 8 bf16 (4 VGPR) MFMA frag
typedef __attribute__((ext_vector_type(8))) unsigned short us8;
typedef __attribute__((ext_vector_type(4))) unsigned int u4;

// fp32 -> bf16 (RNE)
__device__ __forceinline__ unsigned short f2bf(float f) {
    unsigned int u = __float_as_uint(f);
    u = (u + 0x7FFFu + ((u >> 16) & 1u)) >> 16;
    return (unsigned short)u;
}

// ---------------------------------------------------------------------------
// Kernel 1: projections -> bf16. Outputs:
//   qb[b][n][32], kb[b][n][32]  (row-major, K-contiguous for MFMA A/B frags)
//   vtb[b][c][n]                (transposed: row-major in n, for PV B-frags)
// grid = b(4) x nblk(16:256n) x uchunk(10); block 256 (1 thread = 1 n-row, 32 outs)
// ---------------------------------------------------------------------------
__global__ __launch_bounds__(256) void proj_kernel(
    const float* __restrict__ x,
    const float* __restrict__ Wq, const float* __restrict__ bq,
    const float* __restrict__ Wk, const float* __restrict__ bk,
    const float* __restrict__ Wv, const float* __restrict__ bv,
    unsigned short* __restrict__ qb, unsigned short* __restrict__ kb,
    unsigned short* __restrict__ vtb)
{
    __shared__ unsigned short tlds[32][264];   // transpose buffer for v chunks

    const int t    = threadIdx.x;
    const int bid  = blockIdx.x;
    const int b    = bid / 160;
    const int rem  = bid % 160;
    const int nblk = rem / 10;
    const int uc   = rem % 10;
    const int n    = nblk * 256 + t;

    const float* wbase;
    const float* bias;
    if (uc == 0)      { wbase = Wq; bias = bq; }
    else if (uc == 1) { wbase = Wk; bias = bk; }
    else              { wbase = Wv + (size_t)(uc - 2) * 32 * CC; bias = bv + (uc - 2) * 32; }

    float acc[32];
    #pragma unroll
    for (int u = 0; u < 32; ++u) acc[u] = bias[u];

    const float* xb = x + (size_t)b * CC * NN + n;
    for (int cc = 0; cc < CC; cc += 8) {
        float x8[8];
        #pragma unroll
        for (int i = 0; i < 8; ++i) x8[i] = xb[(size_t)(cc + i) * NN];
        #pragma unroll
        for (int u = 0; u < 32; ++u) {
            const float* wr = wbase + (size_t)u * CC + cc;   // wave-uniform -> s_load
            #pragma unroll
            for (int i = 0; i < 8; ++i) acc[u] += wr[i] * x8[i];
        }
    }

    if (uc <= 1) {
        unsigned short* dst = (uc == 0 ? qb : kb) + ((size_t)(b * NN + n)) * CO;
        unsigned int pk[16];
        #pragma unroll
        for (int i = 0; i < 16; ++i)
            pk[i] = (unsigned int)f2bf(acc[2 * i]) | ((unsigned int)f2bf(acc[2 * i + 1]) << 16);
        #pragma unroll
        for (int j = 0; j < 4; ++j) {
            u4 st = { pk[4 * j], pk[4 * j + 1], pk[4 * j + 2], pk[4 * j + 3] };
            *reinterpret_cast<u4*>(dst + j * 8) = st;
        }
    } else {
        // transpose through LDS: lane writes its 32 c-values down a column
        #pragma unroll
        for (int u = 0; u < 32; ++u) tlds[u][t] = f2bf(acc[u]);
        __syncthreads();
        const int cL = t >> 3;              // 0..31
        const int nc = (t & 7) * 32;        // 0..224
        unsigned short* dst = vtb + ((size_t)(b * CC + (uc - 2) * 32 + cL)) * NN + nblk * 256 + nc;
        #pragma unroll
        for (int j = 0; j < 4; ++j) {
            us8 v = *reinterpret_cast<const us8*>(&tlds[cL][nc + j * 8]);
            *reinterpret_cast<us8*>(dst + j * 8) = v;
        }
    }
}

// ---------------------------------------------------------------------------
// Kernel 2: column stats. cinv[b][m] = 1 / sum_n exp(S[n,m]), S = q·k^T (bf16 MFMA).
// No max subtraction: |S| <~ 25 so exp(S) and its 4096-sum fit fp32 comfortably,
// and attn uses the SAME bf16 S so normalization is exact.
// grid = b(4) x mblk(64); block 256 = 4 waves x 16 m-cols each.
// ---------------------------------------------------------------------------
__global__ __launch_bounds__(256) void colstats_kernel(
    const unsigned short* __restrict__ qb, const unsigned short* __restrict__ kb,
    float* __restrict__ cinv)
{
    const int t    = threadIdx.x;
    const int b    = blockIdx.x >> 6;
    const int mblk = blockIdx.x & 63;
    const int l    = t & 63;
    const int w    = t >> 6;
    const int l15  = l & 15;
    const int g4   = l >> 4;
    const int m0   = mblk * 64 + w * 16;

    const unsigned short* qbB = qb + (size_t)b * NN * CO;
    s8 kfrag = *reinterpret_cast<const s8*>(kb + ((size_t)b * NN + m0 + l15) * CO + g4 * 8);

    const f4 z = {0.f, 0.f, 0.f, 0.f};
    float ssum = 0.f;

    for (int n0 = 0; n0 < NN; n0 += 32) {
        s8 a0 = *reinterpret_cast<const s8*>(qbB + (size_t)(n0 + l15) * CO + g4 * 8);
        s8 a1 = *reinterpret_cast<const s8*>(qbB + (size_t)(n0 + 16 + l15) * CO + g4 * 8);
        f4 d0 = __builtin_amdgcn_mfma_f32_16x16x32_bf16(a0, kfrag, z, 0, 0, 0);
        f4 d1 = __builtin_amdgcn_mfma_f32_16x16x32_bf16(a1, kfrag, z, 0, 0, 0);
        #pragma unroll
        for (int r = 0; r < 4; ++r) ssum += __expf(d0[r]) + __expf(d1[r]);
    }

    ssum += __shfl_xor(ssum, 16);
    ssum += __shfl_xor(ssum, 32);
    if (g4 == 0) cinv[b * NN + m0 + l15] = 1.0f / ssum;
}

// ---------------------------------------------------------------------------
// Kernel 3: out[n,c] = sum_m (exp(S[n,m])*cinv[m]) * v[m,c], all GEMMs bf16 MFMA.
// Block = 4 waves, tile 128n x 128c, m-step 64, double-buffered LDS, pipelined:
//   iter i: stage tile i+1 (S->exp->P bf16->plds; reg-staged vT->vlds),
//           prefetch tile i+2 (global->reg), PV-MFMA tile i, one barrier.
// Wave w: S-rows [w*32,+32); PV quadrant (w>>1 n-half, w&1 c-half) = 64n x 64c,
//   4x4 frag reuse: 16 ds_read_b128 -> 32 MFMA per tile.
// ---------------------------------------------------------------------------
__global__ __launch_bounds__(256) void attn_kernel(
    const unsigned short* __restrict__ qb, const unsigned short* __restrict__ kb,
    const unsigned short* __restrict__ vtb, const float* __restrict__ cinv,
    float* __restrict__ out)
{
    __shared__ unsigned short plds[2][128][72];   // P tile  [n][m], pad 72
    __shared__ unsigned short vlds[2][128][72];   // vT tile [c][m], pad 72

    const int t    = threadIdx.x;
    const int bid  = blockIdx.x;
    const int cblk = bid & 1;
    const int nblk = (bid >> 1) & 31;
    const int b    = bid >> 6;
    const int n0   = nblk * 128;
    const int c0   = cblk * 128;
    const int l    = t & 63;
    const int w    = t >> 6;
    const int l15  = l & 15;
    const int g4   = l >> 4;
    const int wr   = w >> 1;       // n-half for PV
    const int wc   = w & 1;        // c-half for PV

    const unsigned short* qbB = qb  + (size_t)b * NN * CO;
    const unsigned short* kbB = kb  + (size_t)b * NN * CO;
    const unsigned short* vtB = vtb + (size_t)b * CC * NN;
    const float*          ciB = cinv + b * NN;

    // persistent q fragments (wave's 32 S-rows)
    s8 qfrag[2];
    #pragma unroll
    for (int a = 0; a < 2; ++a)
        qfrag[a] = *reinterpret_cast<const s8*>(qbB + (size_t)(n0 + w * 32 + a * 16 + l15) * CO + g4 * 8);

    // staging registers for "next" tile
    s8 kreg[4];
    float cir[4];
    s8 vs[4];
    const int vrow = t >> 1;          // c-local row staged by this thread
    const int vhalf = (t & 1) * 32;

    auto loadnext = [&](int mP) {
        #pragma unroll
        for (int j = 0; j < 4; ++j)
            kreg[j] = *reinterpret_cast<const s8*>(kbB + (size_t)(mP + j * 16 + l15) * CO + g4 * 8);
        #pragma unroll
        for (int j = 0; j < 4; ++j) cir[j] = ciB[mP + j * 16 + l15];
        const unsigned short* vsrc = vtB + (size_t)(c0 + vrow) * NN + mP + vhalf;
        #pragma unroll
        for (int j = 0; j < 4; ++j)
            vs[j] = *reinterpret_cast<const s8*>(vsrc + j * 8);
    };

    const f4 z = {0.f, 0.f, 0.f, 0.f};

    auto stage = [&](int buf) {
        // S-MFMA + exp*cinv -> P (bf16) into plds[buf]
        #pragma unroll
        for (int a = 0; a < 2; ++a) {
            #pragma unroll
            for (int j = 0; j < 4; ++j) {
                f4 s = __builtin_amdgcn_mfma_f32_16x16x32_bf16(qfrag[a], kreg[j], z, 0, 0, 0);
                const int row = w * 32 + a * 16 + g4 * 4;
                const int col = j * 16 + l15;
                #pragma unroll
                for (int r = 0; r < 4; ++r) {
                    float p = __expf(s[r]) * cir[j];
                    plds[buf][row + r][col] = f2bf(p);
                }
            }
        }
        // vT registers -> vlds[buf]
        #pragma unroll
        for (int j = 0; j < 4; ++j)
            *reinterpret_cast<s8*>(&vlds[buf][vrow][vhalf + j * 8]) = vs[j];
    };

    f4 acc[4][4];
    #pragma unroll
    for (int a = 0; a < 4; ++a)
        #pragma unroll
        for (int c = 0; c < 4; ++c) acc[a][c] = z;

    // prologue: tile 0 into buf 0, prefetch tile 1
    loadnext(0);
    stage(0);
    loadnext(64);
    __syncthreads();

    for (int i = 0; i < 64; ++i) {
        const int cur = i & 1;
        if (i < 63) {
            stage(cur ^ 1);              // tile i+1 (consumes kreg/cir/vs)
            if (i < 62) loadnext((i + 2) * 64);
        }
        // PV for tile i
        #pragma unroll
        for (int ksl = 0; ksl < 2; ++ksl) {
            s8 pa[4], vb[4];
            #pragma unroll
            for (int a = 0; a < 4; ++a)
                pa[a] = *reinterpret_cast<const s8*>(&plds[cur][wr * 64 + a * 16 + l15][ksl * 32 + g4 * 8]);
            #pragma unroll
            for (int c = 0; c < 4; ++c)
                vb[c] = *reinterpret_cast<const s8*>(&vlds[cur][wc * 64 + c * 16 + l15][ksl * 32 + g4 * 8]);
            #pragma unroll
            for (int a = 0; a < 4; ++a)
                #pragma unroll
                for (int c = 0; c < 4; ++c)
                    acc[a][c] = __builtin_amdgcn_mfma_f32_16x16x32_bf16(pa[a], vb[c], acc[a][c], 0, 0, 0);
        }
        __syncthreads();
    }

    // epilogue: D layout col=lane&15, row=(lane>>4)*4+reg
    #pragma unroll
    for (int a = 0; a < 4; ++a) {
        const int row = n0 + wr * 64 + a * 16 + g4 * 4;
        #pragma unroll
        for (int c = 0; c < 4; ++c) {
            const int col = c0 + wc * 64 + c * 16 + l15;
            #pragma unroll
            for (int r = 0; r < 4; ++r)
                out[((size_t)(b * NN + row + r)) * CC + col] = acc[a][c][r];
        }
    }
}

extern "C" void kernel_launch(void* const* d_in, const int* in_sizes, int n_in,
                              void* d_out, int out_size, void* d_ws, size_t ws_size,
                              hipStream_t stream)
{
    const float* x  = (const float*)d_in[0];
    const float* Wq = (const float*)d_in[1];
    const float* bq = (const float*)d_in[2];
    const float* Wk = (const float*)d_in[3];
    const float* bk = (const float*)d_in[4];
    const float* Wv = (const float*)d_in[5];
    const float* bv = (const float*)d_in[6];
    float* out = (float*)d_out;

    // ws layout: qb(1MB) | kb(1MB) | vtb(8MB) | cinv(64KB)  (all bf16 except cinv)
    unsigned short* qb  = (unsigned short*)d_ws;
    unsigned short* kb  = qb + (size_t)NB * NN * CO;
    unsigned short* vtb = kb + (size_t)NB * NN * CO;
    float*          ci  = (float*)(vtb + (size_t)NB * CC * NN);

    proj_kernel<<<dim3(640), dim3(256), 0, stream>>>(x, Wq, bq, Wk, bk, Wv, bv, qb, kb, vtb);
    colstats_kernel<<<dim3(256), dim3(256), 0, stream>>>(qb, kb, ci);
    attn_kernel<<<dim3(256), dim3(256), 0, stream>>>(qb, kb, vtb, ci, out);
}

// Round 5
// 193.372 us; speedup vs baseline: 5.2503x; 1.4354x over previous
//
#include <hip/hip_runtime.h>
#include <math.h>

#define NB 4
#define CC 256
#define CO 32
#define NN 4096
#define MU 320   // concat projection rows: 32 q + 32 k + 256 v

typedef __attribute__((ext_vector_type(4))) float f4;
typedef __attribute__((ext_vector_type(8))) short s8;          // 8 bf16 MFMA frag
typedef __attribute__((ext_vector_type(8))) unsigned short us8;
typedef __attribute__((ext_vector_type(4))) unsigned short us4;
typedef __attribute__((ext_vector_type(4))) unsigned int u4;

// fp32 -> bf16 (RNE)
__device__ __forceinline__ unsigned short f2bf(float f) {
    unsigned int u = __float_as_uint(f);
    u = (u + 0x7FFFu + ((u >> 16) & 1u)) >> 16;
    return (unsigned short)u;
}

// ---------------------------------------------------------------------------
// prep: blocks [0,256): transpose x[b][c][n] fp32 -> xt[b][n][c] bf16
//        (tile 128n x 128c via LDS);
//       blocks [256,260): concat-convert Wq/Wk/Wv -> Wb[320][256] bf16, fb[320] f32.
// ---------------------------------------------------------------------------
__global__ __launch_bounds__(256) void prep_kernel(
    const float* __restrict__ x,
    const float* __restrict__ Wq, const float* __restrict__ bq,
    const float* __restrict__ Wk, const float* __restrict__ bk,
    const float* __restrict__ Wv, const float* __restrict__ bv,
    unsigned short* __restrict__ xt, unsigned short* __restrict__ Wb,
    float* __restrict__ fb)
{
    const int t = threadIdx.x;
    if (blockIdx.x < 256) {
        __shared__ unsigned short tl[128][136];
        const int b    = blockIdx.x >> 6;
        const int rem  = blockIdx.x & 63;
        const int n0   = (rem >> 1) * 128;
        const int c0   = (rem & 1) * 128;
        const int l32  = t & 31;
        const int cg   = t >> 5;            // 0..7
        #pragma unroll
        for (int i = 0; i < 16; ++i) {
            const int c = i * 8 + cg;
            f4 xv = *reinterpret_cast<const f4*>(x + ((size_t)(b * CC + c0 + c)) * NN + n0 + l32 * 4);
            us4 st = { f2bf(xv[0]), f2bf(xv[1]), f2bf(xv[2]), f2bf(xv[3]) };
            *reinterpret_cast<us4*>(&tl[c][l32 * 4]) = st;
        }
        __syncthreads();
        const int nb_ = t >> 3;             // 0..31
        const int jc  = t & 7;
        #pragma unroll
        for (int np = 0; np < 4; ++np) {
            const int n = nb_ + np * 32;
            #pragma unroll
            for (int jj = 0; jj < 2; ++jj) {
                const int cb = (jc * 2 + jj) * 8;
                us8 v;
                #pragma unroll
                for (int i = 0; i < 8; ++i) v[i] = tl[cb + i][n];
                *reinterpret_cast<us8*>(xt + ((size_t)(b * NN + n0 + n)) * CC + c0 + cb) = v;
            }
        }
    } else {
        const int w = blockIdx.x - 256;     // 0..3, 80 rows each
        for (int i = 0; i < 80; ++i) {
            const int e = w * 20480 + i * 256 + t;
            const int u = e >> 8, c = e & 255;
            float val = (u < 32) ? Wq[u * 256 + c]
                      : (u < 64) ? Wk[(u - 32) * 256 + c]
                                 : Wv[(u - 64) * 256 + c];
            Wb[e] = f2bf(val);
        }
        if (w == 0) {
            for (int u = t; u < MU; u += 256)
                fb[u] = (u < 32) ? bq[u] : (u < 64) ? bk[u - 32] : bv[u - 64];
        }
    }
}

// ---------------------------------------------------------------------------
// projm: MFMA projection. out[u][n] = Wb[u][:]·xt[n][:] + fb[u], u in [0,320).
// grid = b(4) x nblk(64); block = 4 waves, wave owns 16 n-cols (B-frags resident,
// 8 x s8 = K=256), loops 20 u-tiles x 8 MFMA. D: row=u (A-row), col=n (B-row).
// K-slice kk: elements kk*32 + g4*8 (lane-group supplies its own K-chunk).
// ---------------------------------------------------------------------------
__global__ __launch_bounds__(256) void projm_kernel(
    const unsigned short* __restrict__ xt, const unsigned short* __restrict__ Wb,
    const float* __restrict__ fb,
    unsigned short* __restrict__ qb, unsigned short* __restrict__ kb,
    unsigned short* __restrict__ vtb)
{
    const int t   = threadIdx.x;
    const int b   = blockIdx.x >> 6;
    const int nbl = blockIdx.x & 63;
    const int w   = t >> 6;
    const int l   = t & 63;
    const int l15 = l & 15;
    const int g4  = l >> 4;
    const int n   = nbl * 64 + w * 16 + l15;

    s8 bfr[8];
    {
        const unsigned short* xr = xt + ((size_t)(b * NN + n)) * CC;
        #pragma unroll
        for (int kk = 0; kk < 8; ++kk)
            bfr[kk] = *reinterpret_cast<const s8*>(xr + kk * 32 + g4 * 8);
    }

    const f4 z = {0.f, 0.f, 0.f, 0.f};
    unsigned short* qrow = qb + ((size_t)(b * NN + n)) * CO;
    unsigned short* krow = kb + ((size_t)(b * NN + n)) * CO;

    #pragma unroll
    for (int ut = 0; ut < 20; ++ut) {
        const int u0 = ut * 16;
        f4 acc = z;
        #pragma unroll
        for (int kk = 0; kk < 8; ++kk) {
            s8 af = *reinterpret_cast<const s8*>(Wb + (size_t)(u0 + l15) * CC + kk * 32 + g4 * 8);
            acc = __builtin_amdgcn_mfma_f32_16x16x32_bf16(af, bfr[kk], acc, 0, 0, 0);
        }
        f4 bias4 = *reinterpret_cast<const f4*>(fb + u0 + g4 * 4);
        if (u0 < 32) {
            us4 st = { f2bf(acc[0] + bias4[0]), f2bf(acc[1] + bias4[1]),
                       f2bf(acc[2] + bias4[2]), f2bf(acc[3] + bias4[3]) };
            *reinterpret_cast<us4*>(qrow + u0 + g4 * 4) = st;
        } else if (u0 < 64) {
            us4 st = { f2bf(acc[0] + bias4[0]), f2bf(acc[1] + bias4[1]),
                       f2bf(acc[2] + bias4[2]), f2bf(acc[3] + bias4[3]) };
            *reinterpret_cast<us4*>(krow + (u0 - 32) + g4 * 4) = st;
        } else {
            const int cbase = u0 - 64 + g4 * 4;
            #pragma unroll
            for (int r = 0; r < 4; ++r)
                vtb[((size_t)(b * CC + cbase + r)) * NN + n] = f2bf(acc[r] + bias4[r]);
        }
    }
}

// ---------------------------------------------------------------------------
// colstats: cinv[b][m] = 1 / sum_n exp(S[n,m]), S = q·k^T via bf16 MFMA.
// ---------------------------------------------------------------------------
__global__ __launch_bounds__(256) void colstats_kernel(
    const unsigned short* __restrict__ qb, const unsigned short* __restrict__ kb,
    float* __restrict__ cinv)
{
    const int t    = threadIdx.x;
    const int b    = blockIdx.x >> 6;
    const int mblk = blockIdx.x & 63;
    const int l    = t & 63;
    const int w    = t >> 6;
    const int l15  = l & 15;
    const int g4   = l >> 4;
    const int m0   = mblk * 64 + w * 16;

    const unsigned short* qbB = qb + (size_t)b * NN * CO;
    s8 kfrag = *reinterpret_cast<const s8*>(kb + ((size_t)b * NN + m0 + l15) * CO + g4 * 8);

    const f4 z = {0.f, 0.f, 0.f, 0.f};
    float ssum = 0.f;

    for (int n0 = 0; n0 < NN; n0 += 32) {
        s8 a0 = *reinterpret_cast<const s8*>(qbB + (size_t)(n0 + l15) * CO + g4 * 8);
        s8 a1 = *reinterpret_cast<const s8*>(qbB + (size_t)(n0 + 16 + l15) * CO + g4 * 8);
        f4 d0 = __builtin_amdgcn_mfma_f32_16x16x32_bf16(a0, kfrag, z, 0, 0, 0);
        f4 d1 = __builtin_amdgcn_mfma_f32_16x16x32_bf16(a1, kfrag, z, 0, 0, 0);
        #pragma unroll
        for (int r = 0; r < 4; ++r) ssum += __expf(d0[r]) + __expf(d1[r]);
    }

    ssum += __shfl_xor(ssum, 16);
    ssum += __shfl_xor(ssum, 32);
    if (g4 == 0) cinv[b * NN + m0 + l15] = 1.0f / ssum;
}

// ---------------------------------------------------------------------------
// attn: out[n,c] = sum_m (exp(S[n,m])*cinv[m]) * v[m,c], all bf16 MFMA.
// 4 waves, tile 128n x 128c, m-step 64, double-buffered LDS, pipelined.
// ---------------------------------------------------------------------------
__global__ __launch_bounds__(256) void attn_kernel(
    const unsigned short* __restrict__ qb, const unsigned short* __restrict__ kb,
    const unsigned short* __restrict__ vtb, const float* __restrict__ cinv,
    float* __restrict__ out)
{
    __shared__ unsigned short plds[2][128][72];
    __shared__ unsigned short vlds[2][128][72];

    const int t    = threadIdx.x;
    const int bid  = blockIdx.x;
    const int cblk = bid & 1;
    const int nblk = (bid >> 1) & 31;
    const int b    = bid >> 6;
    const int n0   = nblk * 128;
    const int c0   = cblk * 128;
    const int l    = t & 63;
    const int w    = t >> 6;
    const int l15  = l & 15;
    const int g4   = l >> 4;
    const int wr   = w >> 1;
    const int wc   = w & 1;

    const unsigned short* qbB = qb  + (size_t)b * NN * CO;
    const unsigned short* kbB = kb  + (size_t)b * NN * CO;
    const unsigned short* vtB = vtb + (size_t)b * CC * NN;
    const float*          ciB = cinv + b * NN;

    s8 qfrag[2];
    #pragma unroll
    for (int a = 0; a < 2; ++a)
        qfrag[a] = *reinterpret_cast<const s8*>(qbB + (size_t)(n0 + w * 32 + a * 16 + l15) * CO + g4 * 8);

    s8 kreg[4];
    float cir[4];
    s8 vs[4];
    const int vrow = t >> 1;
    const int vhalf = (t & 1) * 32;

    auto loadnext = [&](int mP) {
        #pragma unroll
        for (int j = 0; j < 4; ++j)
            kreg[j] = *reinterpret_cast<const s8*>(kbB + (size_t)(mP + j * 16 + l15) * CO + g4 * 8);
        #pragma unroll
        for (int j = 0; j < 4; ++j) cir[j] = ciB[mP + j * 16 + l15];
        const unsigned short* vsrc = vtB + (size_t)(c0 + vrow) * NN + mP + vhalf;
        #pragma unroll
        for (int j = 0; j < 4; ++j)
            vs[j] = *reinterpret_cast<const s8*>(vsrc + j * 8);
    };

    const f4 z = {0.f, 0.f, 0.f, 0.f};

    auto stage = [&](int buf) {
        #pragma unroll
        for (int a = 0; a < 2; ++a) {
            #pragma unroll
            for (int j = 0; j < 4; ++j) {
                f4 s = __builtin_amdgcn_mfma_f32_16x16x32_bf16(qfrag[a], kreg[j], z, 0, 0, 0);
                const int row = w * 32 + a * 16 + g4 * 4;
                const int col = j * 16 + l15;
                #pragma unroll
                for (int r = 0; r < 4; ++r) {
                    float p = __expf(s[r]) * cir[j];
                    plds[buf][row + r][col] = f2bf(p);
                }
            }
        }
        #pragma unroll
        for (int j = 0; j < 4; ++j)
            *reinterpret_cast<s8*>(&vlds[buf][vrow][vhalf + j * 8]) = vs[j];
    };

    f4 acc[4][4];
    #pragma unroll
    for (int a = 0; a < 4; ++a)
        #pragma unroll
        for (int c = 0; c < 4; ++c) acc[a][c] = z;

    loadnext(0);
    stage(0);
    loadnext(64);
    __syncthreads();

    for (int i = 0; i < 64; ++i) {
        const int cur = i & 1;
        if (i < 63) {
            stage(cur ^ 1);
            if (i < 62) loadnext((i + 2) * 64);
        }
        #pragma unroll
        for (int ksl = 0; ksl < 2; ++ksl) {
            s8 pa[4], vb[4];
            #pragma unroll
            for (int a = 0; a < 4; ++a)
                pa[a] = *reinterpret_cast<const s8*>(&plds[cur][wr * 64 + a * 16 + l15][ksl * 32 + g4 * 8]);
            #pragma unroll
            for (int c = 0; c < 4; ++c)
                vb[c] = *reinterpret_cast<const s8*>(&vlds[cur][wc * 64 + c * 16 + l15][ksl * 32 + g4 * 8]);
            #pragma unroll
            for (int a = 0; a < 4; ++a)
                #pragma unroll
                for (int c = 0; c < 4; ++c)
                    acc[a][c] = __builtin_amdgcn_mfma_f32_16x16x32_bf16(pa[a], vb[c], acc[a][c], 0, 0, 0);
        }
        __syncthreads();
    }

    #pragma unroll
    for (int a = 0; a < 4; ++a) {
        const int row = n0 + wr * 64 + a * 16 + g4 * 4;
        #pragma unroll
        for (int c = 0; c < 4; ++c) {
            const int col = c0 + wc * 64 + c * 16 + l15;
            #pragma unroll
            for (int r = 0; r < 4; ++r)
                out[((size_t)(b * NN + row + r)) * CC + col] = acc[a][c][r];
        }
    }
}

extern "C" void kernel_launch(void* const* d_in, const int* in_sizes, int n_in,
                              void* d_out, int out_size, void* d_ws, size_t ws_size,
                              hipStream_t stream)
{
    const float* x  = (const float*)d_in[0];
    const float* Wq = (const float*)d_in[1];
    const float* bq = (const float*)d_in[2];
    const float* Wk = (const float*)d_in[3];
    const float* bk = (const float*)d_in[4];
    const float* Wv = (const float*)d_in[5];
    const float* bv = (const float*)d_in[6];
    float* out = (float*)d_out;

    // ws layout: qb(1MB) | kb(1MB) | vtb(8MB) | cinv(64KB) | xt(8MB) | Wb(160KB) | fb
    unsigned short* qb  = (unsigned short*)d_ws;
    unsigned short* kb  = qb + (size_t)NB * NN * CO;
    unsigned short* vtb = kb + (size_t)NB * NN * CO;
    float*          ci  = (float*)(vtb + (size_t)NB * CC * NN);
    unsigned short* xt  = (unsigned short*)(ci + (size_t)NB * NN);
    unsigned short* Wb  = xt + (size_t)NB * NN * CC;
    float*          fb  = (float*)(Wb + (size_t)MU * CC);

    prep_kernel<<<dim3(260), dim3(256), 0, stream>>>(x, Wq, bq, Wk, bk, Wv, bv, xt, Wb, fb);
    projm_kernel<<<dim3(256), dim3(256), 0, stream>>>(xt, Wb, fb, qb, kb, vtb);
    colstats_kernel<<<dim3(256), dim3(256), 0, stream>>>(qb, kb, ci);
    attn_kernel<<<dim3(256), dim3(256), 0, stream>>>(qb, kb, vtb, ci, out);
}

// Round 6
// 173.015 us; speedup vs baseline: 5.8681x; 1.1177x over previous
//
#include <hip/hip_runtime.h>
#include <math.h>

#define NB 4
#define CC 256
#define CO 32
#define NN 4096
#define MU 320   // concat projection rows: 32 q + 32 k + 256 v

typedef __attribute__((ext_vector_type(4))) float f4;
typedef __attribute__((ext_vector_type(8))) short s8;          // 8 bf16 MFMA frag
typedef __attribute__((ext_vector_type(8))) unsigned short us8;
typedef __attribute__((ext_vector_type(4))) unsigned short us4;
typedef __attribute__((ext_vector_type(2))) unsigned int u2;

// fp32 -> bf16 (RNE)
__device__ __forceinline__ unsigned short f2bf(float f) {
    unsigned int u = __float_as_uint(f);
    u = (u + 0x7FFFu + ((u >> 16) & 1u)) >> 16;
    return (unsigned short)u;
}
__device__ __forceinline__ unsigned int pk2(float a, float b) {
    return (unsigned int)f2bf(a) | ((unsigned int)f2bf(b) << 16);
}

// ---------------------------------------------------------------------------
// prep: blocks [0,512): transpose x[b][c][n] fp32 -> xt[b][n][c] bf16.
//   Tile 64n x 128c staged as fp32 LDS [n][c] pitch 132 dw (16B-aligned rows,
//   writes 8-way-at-floor, reads floor-limited b128) -- replaces the old
//   16-way-conflicted column gather.
// blocks [512,516): concat-convert Wq/Wk/Wv -> Wb[320][256] bf16, fb[320] f32.
// ---------------------------------------------------------------------------
__global__ __launch_bounds__(256) void prep_kernel(
    const float* __restrict__ x,
    const float* __restrict__ Wq, const float* __restrict__ bq,
    const float* __restrict__ Wk, const float* __restrict__ bk,
    const float* __restrict__ Wv, const float* __restrict__ bv,
    unsigned short* __restrict__ xt, unsigned short* __restrict__ Wb,
    float* __restrict__ fb)
{
    const int t = threadIdx.x;
    if (blockIdx.x < 512) {
        __shared__ float ldsf[64][132];
        const int b   = blockIdx.x >> 7;
        const int rem = blockIdx.x & 127;
        const int n0  = (rem >> 1) * 64;
        const int c0  = (rem & 1) * 128;
        const int nl  = (t & 15) * 4;
        const int cr  = t >> 4;                 // 0..15
        #pragma unroll
        for (int cp = 0; cp < 8; ++cp) {
            const int c = cr + cp * 16;
            f4 xv = *reinterpret_cast<const f4*>(x + ((size_t)(b * CC + c0 + c)) * NN + n0 + nl);
            #pragma unroll
            for (int j = 0; j < 4; ++j) ldsf[nl + j][c] = xv[j];
        }
        __syncthreads();
        const int cl = (t & 15) * 8;
        #pragma unroll
        for (int np = 0; np < 4; ++np) {
            const int n = cr + np * 16;
            f4 a  = *reinterpret_cast<const f4*>(&ldsf[n][cl]);
            f4 bb = *reinterpret_cast<const f4*>(&ldsf[n][cl + 4]);
            us8 o = { f2bf(a[0]), f2bf(a[1]), f2bf(a[2]), f2bf(a[3]),
                      f2bf(bb[0]), f2bf(bb[1]), f2bf(bb[2]), f2bf(bb[3]) };
            *reinterpret_cast<us8*>(xt + ((size_t)(b * NN + n0 + n)) * CC + c0 + cl) = o;
        }
    } else {
        const int w = blockIdx.x - 512;         // 0..3, 80 rows each
        for (int i = 0; i < 80; ++i) {
            const int e = w * 20480 + i * 256 + t;
            const int u = e >> 8, c = e & 255;
            float val = (u < 32) ? Wq[u * 256 + c]
                      : (u < 64) ? Wk[(u - 32) * 256 + c]
                                 : Wv[(u - 64) * 256 + c];
            Wb[e] = f2bf(val);
        }
        if (w == 0) {
            for (int u = t; u < MU; u += 256)
                fb[u] = (u < 32) ? bq[u] : (u < 64) ? bk[u - 32] : bv[u - 64];
        }
    }
}

// ---------------------------------------------------------------------------
// projm: MFMA projection. out[u][n] = Wb[u][:]·xt[n][:] + fb[u], u in [0,320).
// (unchanged from round 5 -- verified good)
// ---------------------------------------------------------------------------
__global__ __launch_bounds__(256) void projm_kernel(
    const unsigned short* __restrict__ xt, const unsigned short* __restrict__ Wb,
    const float* __restrict__ fb,
    unsigned short* __restrict__ qb, unsigned short* __restrict__ kb,
    unsigned short* __restrict__ vtb)
{
    const int t   = threadIdx.x;
    const int b   = blockIdx.x >> 6;
    const int nbl = blockIdx.x & 63;
    const int w   = t >> 6;
    const int l   = t & 63;
    const int l15 = l & 15;
    const int g4  = l >> 4;
    const int n   = nbl * 64 + w * 16 + l15;

    s8 bfr[8];
    {
        const unsigned short* xr = xt + ((size_t)(b * NN + n)) * CC;
        #pragma unroll
        for (int kk = 0; kk < 8; ++kk)
            bfr[kk] = *reinterpret_cast<const s8*>(xr + kk * 32 + g4 * 8);
    }

    const f4 z = {0.f, 0.f, 0.f, 0.f};
    unsigned short* qrow = qb + ((size_t)(b * NN + n)) * CO;
    unsigned short* krow = kb + ((size_t)(b * NN + n)) * CO;

    #pragma unroll
    for (int ut = 0; ut < 20; ++ut) {
        const int u0 = ut * 16;
        f4 acc = z;
        #pragma unroll
        for (int kk = 0; kk < 8; ++kk) {
            s8 af = *reinterpret_cast<const s8*>(Wb + (size_t)(u0 + l15) * CC + kk * 32 + g4 * 8);
            acc = __builtin_amdgcn_mfma_f32_16x16x32_bf16(af, bfr[kk], acc, 0, 0, 0);
        }
        f4 bias4 = *reinterpret_cast<const f4*>(fb + u0 + g4 * 4);
        if (u0 < 32) {
            us4 st = { f2bf(acc[0] + bias4[0]), f2bf(acc[1] + bias4[1]),
                       f2bf(acc[2] + bias4[2]), f2bf(acc[3] + bias4[3]) };
            *reinterpret_cast<us4*>(qrow + u0 + g4 * 4) = st;
        } else if (u0 < 64) {
            us4 st = { f2bf(acc[0] + bias4[0]), f2bf(acc[1] + bias4[1]),
                       f2bf(acc[2] + bias4[2]), f2bf(acc[3] + bias4[3]) };
            *reinterpret_cast<us4*>(krow + (u0 - 32) + g4 * 4) = st;
        } else {
            const int cbase = u0 - 64 + g4 * 4;
            #pragma unroll
            for (int r = 0; r < 4; ++r)
                vtb[((size_t)(b * CC + cbase + r)) * NN + n] = f2bf(acc[r] + bias4[r]);
        }
    }
}

// ---------------------------------------------------------------------------
// colstats: cinv[b][m] = 1 / sum_n exp(S[n,m]).  512 blocks (2/CU): block owns
// 32 m; waves split (m-half, n-half); cross-wave combine via LDS.
// ---------------------------------------------------------------------------
__global__ __launch_bounds__(256) void colstats_kernel(
    const unsigned short* __restrict__ qb, const unsigned short* __restrict__ kb,
    float* __restrict__ cinv)
{
    __shared__ float red[4][16];
    const int t   = threadIdx.x;
    const int b   = blockIdx.x >> 7;
    const int mb  = blockIdx.x & 127;
    const int l   = t & 63;
    const int w   = t >> 6;
    const int l15 = l & 15;
    const int g4  = l >> 4;
    const int m   = mb * 32 + (w & 1) * 16 + l15;
    const int nh  = w >> 1;

    const unsigned short* qbB = qb + (size_t)b * NN * CO;
    s8 kfrag = *reinterpret_cast<const s8*>(kb + ((size_t)b * NN + m) * CO + g4 * 8);

    const f4 z = {0.f, 0.f, 0.f, 0.f};
    float ssum = 0.f;

    const int nbeg = nh * 2048, nend = nbeg + 2048;
    for (int n0 = nbeg; n0 < nend; n0 += 32) {
        s8 a0 = *reinterpret_cast<const s8*>(qbB + (size_t)(n0 + l15) * CO + g4 * 8);
        s8 a1 = *reinterpret_cast<const s8*>(qbB + (size_t)(n0 + 16 + l15) * CO + g4 * 8);
        f4 d0 = __builtin_amdgcn_mfma_f32_16x16x32_bf16(a0, kfrag, z, 0, 0, 0);
        f4 d1 = __builtin_amdgcn_mfma_f32_16x16x32_bf16(a1, kfrag, z, 0, 0, 0);
        #pragma unroll
        for (int r = 0; r < 4; ++r) ssum += __expf(d0[r]) + __expf(d1[r]);
    }

    ssum += __shfl_xor(ssum, 16);
    ssum += __shfl_xor(ssum, 32);
    if (l < 16) red[w][l15] = ssum;
    __syncthreads();
    if (w < 2 && l < 16) {
        float tot = red[w][l15] + red[w + 2][l15];
        cinv[b * NN + mb * 32 + w * 16 + l15] = 1.0f / tot;
    }
}

// ---------------------------------------------------------------------------
// attn: out[n,c] = sum_m (exp(S[n,m])*cinv[m]) * v[m,c].
// Tile 64n x 128c, grid 512 (2 blocks/CU).  Swapped S-MFMA: d = mfma(K,Q)
// puts 4 consecutive m in D-regs (n fixed per lane) -> P packs into one b64
// LDS write per j; cinv is a clean f4 load.  PV: wave quadrant 32n x 64c with
// 2x4 frag reuse.  Double-buffered LDS (55 KB), one barrier/tile.
// ---------------------------------------------------------------------------
__global__ __launch_bounds__(256) void attn_kernel(
    const unsigned short* __restrict__ qb, const unsigned short* __restrict__ kb,
    const unsigned short* __restrict__ vtb, const float* __restrict__ cinv,
    float* __restrict__ out)
{
    __shared__ unsigned short plds[2][64][72];    // P tile  [n][m]
    __shared__ unsigned short vlds[2][128][72];   // vT tile [c][m]

    const int t    = threadIdx.x;
    const int bid  = blockIdx.x;
    const int cblk = bid & 1;
    const int nblk = (bid >> 1) & 63;
    const int b    = bid >> 7;
    const int n0   = nblk * 64;
    const int c0   = cblk * 128;
    const int l    = t & 63;
    const int w    = t >> 6;
    const int l15  = l & 15;
    const int g4   = l >> 4;
    const int wr   = w >> 1;       // PV n-half
    const int wc   = w & 1;        // PV c-half

    const unsigned short* qbB = qb  + (size_t)b * NN * CO;
    const unsigned short* kbB = kb  + (size_t)b * NN * CO;
    const unsigned short* vtB = vtb + (size_t)b * CC * NN;
    const float*          ciB = cinv + b * NN;

    // wave's 16 S-rows (B-operand of swapped MFMA)
    s8 qfrag = *reinterpret_cast<const s8*>(qbB + (size_t)(n0 + w * 16 + l15) * CO + g4 * 8);

    s8 kreg[4];
    f4 civ[4];
    s8 vs[4];
    const int vrow  = t >> 1;          // c-local row staged by this thread
    const int vhalf = (t & 1) * 32;

    auto loadnext = [&](int mP) {
        #pragma unroll
        for (int j = 0; j < 4; ++j)
            kreg[j] = *reinterpret_cast<const s8*>(kbB + (size_t)(mP + j * 16 + l15) * CO + g4 * 8);
        #pragma unroll
        for (int j = 0; j < 4; ++j)
            civ[j] = *reinterpret_cast<const f4*>(ciB + mP + j * 16 + g4 * 4);
        const unsigned short* vsrc = vtB + (size_t)(c0 + vrow) * NN + mP + vhalf;
        #pragma unroll
        for (int j = 0; j < 4; ++j)
            vs[j] = *reinterpret_cast<const s8*>(vsrc + j * 8);
    };

    const f4 z = {0.f, 0.f, 0.f, 0.f};

    auto stage = [&](int buf) {
        // swapped S: d = mfma(K_rows(m), Q_rows(n)) -> D[m][n]:
        //   thread (l15,g4): n = w*16+l15 (col), m = j*16 + g4*4 + r (row)
        #pragma unroll
        for (int j = 0; j < 4; ++j) {
            f4 d = __builtin_amdgcn_mfma_f32_16x16x32_bf16(kreg[j], qfrag, z, 0, 0, 0);
            u2 pw = { pk2(__expf(d[0]) * civ[j][0], __expf(d[1]) * civ[j][1]),
                      pk2(__expf(d[2]) * civ[j][2], __expf(d[3]) * civ[j][3]) };
            *reinterpret_cast<u2*>(&plds[buf][w * 16 + l15][j * 16 + g4 * 4]) = pw;
        }
        #pragma unroll
        for (int j = 0; j < 4; ++j)
            *reinterpret_cast<s8*>(&vlds[buf][vrow][vhalf + j * 8]) = vs[j];
    };

    f4 acc[2][4];
    #pragma unroll
    for (int a = 0; a < 2; ++a)
        #pragma unroll
        for (int c = 0; c < 4; ++c) acc[a][c] = z;

    loadnext(0);
    stage(0);
    loadnext(64);
    __syncthreads();

    for (int i = 0; i < 64; ++i) {
        const int cur = i & 1;
        if (i < 63) {
            stage(cur ^ 1);
            if (i < 62) loadnext((i + 2) * 64);
        }
        #pragma unroll
        for (int ksl = 0; ksl < 2; ++ksl) {
            s8 pa[2], vb[4];
            #pragma unroll
            for (int a = 0; a < 2; ++a)
                pa[a] = *reinterpret_cast<const s8*>(&plds[cur][wr * 32 + a * 16 + l15][ksl * 32 + g4 * 8]);
            #pragma unroll
            for (int c = 0; c < 4; ++c)
                vb[c] = *reinterpret_cast<const s8*>(&vlds[cur][wc * 64 + c * 16 + l15][ksl * 32 + g4 * 8]);
            #pragma unroll
            for (int a = 0; a < 2; ++a)
                #pragma unroll
                for (int c = 0; c < 4; ++c)
                    acc[a][c] = __builtin_amdgcn_mfma_f32_16x16x32_bf16(pa[a], vb[c], acc[a][c], 0, 0, 0);
        }
        __syncthreads();
    }

    // D layout: col = lane&15 (c), row = g4*4 + r (n)
    #pragma unroll
    for (int a = 0; a < 2; ++a) {
        const int row = n0 + wr * 32 + a * 16 + g4 * 4;
        #pragma unroll
        for (int c = 0; c < 4; ++c) {
            const int col = c0 + wc * 64 + c * 16 + l15;
            #pragma unroll
            for (int r = 0; r < 4; ++r)
                out[((size_t)(b * NN + row + r)) * CC + col] = acc[a][c][r];
        }
    }
}

extern "C" void kernel_launch(void* const* d_in, const int* in_sizes, int n_in,
                              void* d_out, int out_size, void* d_ws, size_t ws_size,
                              hipStream_t stream)
{
    const float* x  = (const float*)d_in[0];
    const float* Wq = (const float*)d_in[1];
    const float* bq = (const float*)d_in[2];
    const float* Wk = (const float*)d_in[3];
    const float* bk = (const float*)d_in[4];
    const float* Wv = (const float*)d_in[5];
    const float* bv = (const float*)d_in[6];
    float* out = (float*)d_out;

    // ws layout: qb(1MB) | kb(1MB) | vtb(8MB) | cinv(64KB) | xt(8MB) | Wb(160KB) | fb
    unsigned short* qb  = (unsigned short*)d_ws;
    unsigned short* kb  = qb + (size_t)NB * NN * CO;
    unsigned short* vtb = kb + (size_t)NB * NN * CO;
    float*          ci  = (float*)(vtb + (size_t)NB * CC * NN);
    unsigned short* xt  = (unsigned short*)(ci + (size_t)NB * NN);
    unsigned short* Wb  = xt + (size_t)NB * NN * CC;
    float*          fb  = (float*)(Wb + (size_t)MU * CC);

    prep_kernel<<<dim3(516), dim3(256), 0, stream>>>(x, Wq, bq, Wk, bk, Wv, bv, xt, Wb, fb);
    projm_kernel<<<dim3(256), dim3(256), 0, stream>>>(xt, Wb, fb, qb, kb, vtb);
    colstats_kernel<<<dim3(512), dim3(256), 0, stream>>>(qb, kb, ci);
    attn_kernel<<<dim3(512), dim3(256), 0, stream>>>(qb, kb, vtb, ci, out);
}

// Round 8
// 169.184 us; speedup vs baseline: 6.0010x; 1.0226x over previous
//
#include <hip/hip_runtime.h>
#include <math.h>

#define NB 4
#define CC 256
#define CO 32
#define NN 4096
#define MU 320   // concat projection rows: 32 q + 32 k + 256 v

typedef __attribute__((ext_vector_type(4))) float f4;
typedef __attribute__((ext_vector_type(8))) short s8;          // 8 bf16 MFMA frag
typedef __attribute__((ext_vector_type(8))) unsigned short us8;
typedef __attribute__((ext_vector_type(4))) unsigned short us4;
typedef __attribute__((ext_vector_type(2))) unsigned int u2;

// fp32 -> bf16 (RNE)
__device__ __forceinline__ unsigned short f2bf(float f) {
    unsigned int u = __float_as_uint(f);
    u = (u + 0x7FFFu + ((u >> 16) & 1u)) >> 16;
    return (unsigned short)u;
}
__device__ __forceinline__ unsigned int pk2(float a, float b) {
    return (unsigned int)f2bf(a) | ((unsigned int)f2bf(b) << 16);
}
// XOR-swizzled byte offset within a 128B-row LDS tile (T2 recipe).
// Mask bits 4-6 only: any 8/16B-aligned vector access stays contiguous.
__device__ __forceinline__ int swz128(int row, int colByte) {
    return row * 128 + (colByte ^ ((row & 7) << 4));
}

// ---------------------------------------------------------------------------
// prep: blocks [0,512): transpose x[b][c][n] fp32 -> xt[b][n][c] bf16.
// blocks [512,516): concat-convert Wq/Wk/Wv -> Wb[320][256] bf16, fb[320] f32.
// (byte-identical to round-6 passing version)
// ---------------------------------------------------------------------------
__global__ __launch_bounds__(256) void prep_kernel(
    const float* __restrict__ x,
    const float* __restrict__ Wq, const float* __restrict__ bq,
    const float* __restrict__ Wk, const float* __restrict__ bk,
    const float* __restrict__ Wv, const float* __restrict__ bv,
    unsigned short* __restrict__ xt, unsigned short* __restrict__ Wb,
    float* __restrict__ fb)
{
    const int t = threadIdx.x;
    if (blockIdx.x < 512) {
        __shared__ float ldsf[64][132];
        const int b   = blockIdx.x >> 7;
        const int rem = blockIdx.x & 127;
        const int n0  = (rem >> 1) * 64;
        const int c0  = (rem & 1) * 128;
        const int nl  = (t & 15) * 4;
        const int cr  = t >> 4;                 // 0..15
        #pragma unroll
        for (int cp = 0; cp < 8; ++cp) {
            const int c = cr + cp * 16;
            f4 xv = *reinterpret_cast<const f4*>(x + ((size_t)(b * CC + c0 + c)) * NN + n0 + nl);
            #pragma unroll
            for (int j = 0; j < 4; ++j) ldsf[nl + j][c] = xv[j];
        }
        __syncthreads();
        const int cl = (t & 15) * 8;
        #pragma unroll
        for (int np = 0; np < 4; ++np) {
            const int n = cr + np * 16;
            f4 a  = *reinterpret_cast<const f4*>(&ldsf[n][cl]);
            f4 bb = *reinterpret_cast<const f4*>(&ldsf[n][cl + 4]);
            us8 o = { f2bf(a[0]), f2bf(a[1]), f2bf(a[2]), f2bf(a[3]),
                      f2bf(bb[0]), f2bf(bb[1]), f2bf(bb[2]), f2bf(bb[3]) };
            *reinterpret_cast<us8*>(xt + ((size_t)(b * NN + n0 + n)) * CC + c0 + cl) = o;
        }
    } else {
        const int w = blockIdx.x - 512;         // 0..3, 80 rows each
        for (int i = 0; i < 80; ++i) {
            const int e = w * 20480 + i * 256 + t;
            const int u = e >> 8, c = e & 255;
            float val = (u < 32) ? Wq[u * 256 + c]
                      : (u < 64) ? Wk[(u - 32) * 256 + c]
                                 : Wv[(u - 64) * 256 + c];
            Wb[e] = f2bf(val);
        }
        if (w == 0) {
            for (int u = t; u < MU; u += 256)
                fb[u] = (u < 32) ? bq[u] : (u < 64) ? bk[u - 32] : bv[u - 64];
        }
    }
}

// ---------------------------------------------------------------------------
// projm: MFMA projection (byte-identical to round-6 passing version).
// ---------------------------------------------------------------------------
__global__ __launch_bounds__(256) void projm_kernel(
    const unsigned short* __restrict__ xt, const unsigned short* __restrict__ Wb,
    const float* __restrict__ fb,
    unsigned short* __restrict__ qb, unsigned short* __restrict__ kb,
    unsigned short* __restrict__ vtb)
{
    const int t   = threadIdx.x;
    const int b   = blockIdx.x >> 6;
    const int nbl = blockIdx.x & 63;
    const int w   = t >> 6;
    const int l   = t & 63;
    const int l15 = l & 15;
    const int g4  = l >> 4;
    const int n   = nbl * 64 + w * 16 + l15;

    s8 bfr[8];
    {
        const unsigned short* xr = xt + ((size_t)(b * NN + n)) * CC;
        #pragma unroll
        for (int kk = 0; kk < 8; ++kk)
            bfr[kk] = *reinterpret_cast<const s8*>(xr + kk * 32 + g4 * 8);
    }

    const f4 z = {0.f, 0.f, 0.f, 0.f};
    unsigned short* qrow = qb + ((size_t)(b * NN + n)) * CO;
    unsigned short* krow = kb + ((size_t)(b * NN + n)) * CO;

    #pragma unroll
    for (int ut = 0; ut < 20; ++ut) {
        const int u0 = ut * 16;
        f4 acc = z;
        #pragma unroll
        for (int kk = 0; kk < 8; ++kk) {
            s8 af = *reinterpret_cast<const s8*>(Wb + (size_t)(u0 + l15) * CC + kk * 32 + g4 * 8);
            acc = __builtin_amdgcn_mfma_f32_16x16x32_bf16(af, bfr[kk], acc, 0, 0, 0);
        }
        f4 bias4 = *reinterpret_cast<const f4*>(fb + u0 + g4 * 4);
        if (u0 < 32) {
            us4 st = { f2bf(acc[0] + bias4[0]), f2bf(acc[1] + bias4[1]),
                       f2bf(acc[2] + bias4[2]), f2bf(acc[3] + bias4[3]) };
            *reinterpret_cast<us4*>(qrow + u0 + g4 * 4) = st;
        } else if (u0 < 64) {
            us4 st = { f2bf(acc[0] + bias4[0]), f2bf(acc[1] + bias4[1]),
                       f2bf(acc[2] + bias4[2]), f2bf(acc[3] + bias4[3]) };
            *reinterpret_cast<us4*>(krow + (u0 - 32) + g4 * 4) = st;
        } else {
            const int cbase = u0 - 64 + g4 * 4;
            #pragma unroll
            for (int r = 0; r < 4; ++r)
                vtb[((size_t)(b * CC + cbase + r)) * NN + n] = f2bf(acc[r] + bias4[r]);
        }
    }
}

// ---------------------------------------------------------------------------
// colstats: cinv[b][m] = 1 / sum_n exp(S[n,m])  (round-6 passing version).
// ---------------------------------------------------------------------------
__global__ __launch_bounds__(256) void colstats_kernel(
    const unsigned short* __restrict__ qb, const unsigned short* __restrict__ kb,
    float* __restrict__ cinv)
{
    __shared__ float red[4][16];
    const int t   = threadIdx.x;
    const int b   = blockIdx.x >> 7;
    const int mb  = blockIdx.x & 127;
    const int l   = t & 63;
    const int w   = t >> 6;
    const int l15 = l & 15;
    const int g4  = l >> 4;
    const int m   = mb * 32 + (w & 1) * 16 + l15;
    const int nh  = w >> 1;

    const unsigned short* qbB = qb + (size_t)b * NN * CO;
    s8 kfrag = *reinterpret_cast<const s8*>(kb + ((size_t)b * NN + m) * CO + g4 * 8);

    const f4 z = {0.f, 0.f, 0.f, 0.f};
    float ssum = 0.f;

    const int nbeg = nh * 2048, nend = nbeg + 2048;
    for (int n0 = nbeg; n0 < nend; n0 += 32) {
        s8 a0 = *reinterpret_cast<const s8*>(qbB + (size_t)(n0 + l15) * CO + g4 * 8);
        s8 a1 = *reinterpret_cast<const s8*>(qbB + (size_t)(n0 + 16 + l15) * CO + g4 * 8);
        f4 d0 = __builtin_amdgcn_mfma_f32_16x16x32_bf16(a0, kfrag, z, 0, 0, 0);
        f4 d1 = __builtin_amdgcn_mfma_f32_16x16x32_bf16(a1, kfrag, z, 0, 0, 0);
        #pragma unroll
        for (int r = 0; r < 4; ++r) ssum += __expf(d0[r]) + __expf(d1[r]);
    }

    ssum += __shfl_xor(ssum, 16);
    ssum += __shfl_xor(ssum, 32);
    if (l < 16) red[w][l15] = ssum;
    __syncthreads();
    if (w < 2 && l < 16) {
        float tot = red[w][l15] + red[w + 2][l15];
        cinv[b * NN + mb * 32 + w * 16 + l15] = 1.0f / tot;
    }
}

// ---------------------------------------------------------------------------
// attn: round-6 passing structure (64n x 128c tile, swapped S-MFMA, civ
// multiply, double-buffer) + ONE change: XOR-swizzled LDS addressing on
// plds/vlds (write and read), plus setprio around the PV MFMA cluster.
// ---------------------------------------------------------------------------
__global__ __launch_bounds__(256) void attn_kernel(
    const unsigned short* __restrict__ qb, const unsigned short* __restrict__ kb,
    const unsigned short* __restrict__ vtb, const float* __restrict__ cinv,
    float* __restrict__ out)
{
    __shared__ __align__(16) char plds[2][64 * 128];    // P tile  [n][m] bf16, swizzled
    __shared__ __align__(16) char vlds[2][128 * 128];   // vT tile [c][m] bf16, swizzled

    const int t    = threadIdx.x;
    const int bid  = blockIdx.x;
    const int cblk = bid & 1;
    const int nblk = (bid >> 1) & 63;
    const int b    = bid >> 7;
    const int n0   = nblk * 64;
    const int c0   = cblk * 128;
    const int l    = t & 63;
    const int w    = t >> 6;
    const int l15  = l & 15;
    const int g4   = l >> 4;
    const int wr   = w >> 1;       // PV n-half
    const int wc   = w & 1;        // PV c-half

    const unsigned short* qbB = qb  + (size_t)b * NN * CO;
    const unsigned short* kbB = kb  + (size_t)b * NN * CO;
    const unsigned short* vtB = vtb + (size_t)b * CC * NN;
    const float*          ciB = cinv + b * NN;

    // wave's 16 S-rows (B-operand of swapped MFMA)
    s8 qfrag = *reinterpret_cast<const s8*>(qbB + (size_t)(n0 + w * 16 + l15) * CO + g4 * 8);

    s8 kreg[4];
    f4 civ[4];
    s8 vs[4];
    const int vrow  = t >> 1;          // c-local row staged by this thread
    const int vhalf = (t & 1) * 64;    // byte offset of m-half in LDS row

    auto loadnext = [&](int mP) {
        #pragma unroll
        for (int j = 0; j < 4; ++j)
            kreg[j] = *reinterpret_cast<const s8*>(kbB + (size_t)(mP + j * 16 + l15) * CO + g4 * 8);
        #pragma unroll
        for (int j = 0; j < 4; ++j)
            civ[j] = *reinterpret_cast<const f4*>(ciB + mP + j * 16 + g4 * 4);
        const unsigned short* vsrc = vtB + (size_t)(c0 + vrow) * NN + mP + (t & 1) * 32;
        #pragma unroll
        for (int j = 0; j < 4; ++j)
            vs[j] = *reinterpret_cast<const s8*>(vsrc + j * 8);
    };

    const f4 z = {0.f, 0.f, 0.f, 0.f};

    auto stage = [&](int buf) {
        // swapped S: d = mfma(K_rows(m), Q_rows(n)):
        //   lane (l15,g4): n = w*16+l15, m = j*16 + g4*4 + r
        #pragma unroll
        for (int j = 0; j < 4; ++j) {
            f4 d = __builtin_amdgcn_mfma_f32_16x16x32_bf16(kreg[j], qfrag, z, 0, 0, 0);
            u2 pw = { pk2(__expf(d[0]) * civ[j][0], __expf(d[1]) * civ[j][1]),
                      pk2(__expf(d[2]) * civ[j][2], __expf(d[3]) * civ[j][3]) };
            *reinterpret_cast<u2*>(plds[buf] + swz128(w * 16 + l15, j * 32 + g4 * 8)) = pw;
        }
        #pragma unroll
        for (int j = 0; j < 4; ++j)
            *reinterpret_cast<s8*>(vlds[buf] + swz128(vrow, vhalf + j * 16)) = vs[j];
    };

    f4 acc[2][4];
    #pragma unroll
    for (int a = 0; a < 2; ++a)
        #pragma unroll
        for (int c = 0; c < 4; ++c) acc[a][c] = z;

    loadnext(0);
    stage(0);
    loadnext(64);
    __syncthreads();

    for (int i = 0; i < 64; ++i) {
        const int cur = i & 1;
        if (i < 63) {
            stage(cur ^ 1);
            if (i < 62) loadnext((i + 2) * 64);
        }
        #pragma unroll
        for (int ksl = 0; ksl < 2; ++ksl) {
            s8 pa[2], vb[4];
            #pragma unroll
            for (int a = 0; a < 2; ++a)
                pa[a] = *reinterpret_cast<const s8*>(
                    plds[cur] + swz128(wr * 32 + a * 16 + l15, ksl * 64 + g4 * 16));
            #pragma unroll
            for (int c = 0; c < 4; ++c)
                vb[c] = *reinterpret_cast<const s8*>(
                    vlds[cur] + swz128(wc * 64 + c * 16 + l15, ksl * 64 + g4 * 16));
            __builtin_amdgcn_s_setprio(1);
            #pragma unroll
            for (int a = 0; a < 2; ++a)
                #pragma unroll
                for (int c = 0; c < 4; ++c)
                    acc[a][c] = __builtin_amdgcn_mfma_f32_16x16x32_bf16(pa[a], vb[c], acc[a][c], 0, 0, 0);
            __builtin_amdgcn_s_setprio(0);
        }
        __syncthreads();
    }

    // D layout: col = lane&15 (c), row = g4*4 + r (n)
    #pragma unroll
    for (int a = 0; a < 2; ++a) {
        const int row = n0 + wr * 32 + a * 16 + g4 * 4;
        #pragma unroll
        for (int c = 0; c < 4; ++c) {
            const int col = c0 + wc * 64 + c * 16 + l15;
            #pragma unroll
            for (int r = 0; r < 4; ++r)
                out[((size_t)(b * NN + row + r)) * CC + col] = acc[a][c][r];
        }
    }
}

extern "C" void kernel_launch(void* const* d_in, const int* in_sizes, int n_in,
                              void* d_out, int out_size, void* d_ws, size_t ws_size,
                              hipStream_t stream)
{
    const float* x  = (const float*)d_in[0];
    const float* Wq = (const float*)d_in[1];
    const float* bq = (const float*)d_in[2];
    const float* Wk = (const float*)d_in[3];
    const float* bk = (const float*)d_in[4];
    const float* Wv = (const float*)d_in[5];
    const float* bv = (const float*)d_in[6];
    float* out = (float*)d_out;

    // ws layout: qb(1MB) | kb(1MB) | vtb(8MB) | cinv(64KB) | xt(8MB) | Wb(160KB) | fb
    unsigned short* qb  = (unsigned short*)d_ws;
    unsigned short* kb  = qb + (size_t)NB * NN * CO;
    unsigned short* vtb = kb + (size_t)NB * NN * CO;
    float*          ci  = (float*)(vtb + (size_t)NB * CC * NN);
    unsigned short* xt  = (unsigned short*)(ci + (size_t)NB * NN);
    unsigned short* Wb  = xt + (size_t)NB * NN * CC;
    float*          fb  = (float*)(Wb + (size_t)MU * CC);

    prep_kernel<<<dim3(516), dim3(256), 0, stream>>>(x, Wq, bq, Wk, bk, Wv, bv, xt, Wb, fb);
    projm_kernel<<<dim3(256), dim3(256), 0, stream>>>(xt, Wb, fb, qb, kb, vtb);
    colstats_kernel<<<dim3(512), dim3(256), 0, stream>>>(qb, kb, ci);
    attn_kernel<<<dim3(512), dim3(256), 0, stream>>>(qb, kb, vtb, ci, out);
}

// Round 10
// 159.074 us; speedup vs baseline: 6.3824x; 1.0636x over previous
//
#include <hip/hip_runtime.h>
#include <math.h>

#define NB 4
#define CC 256
#define CO 32
#define NN 4096
#define MU 320   // concat projection rows: 32 q + 32 k + 256 v
#define LOG2E 1.44269504088896f

typedef __attribute__((ext_vector_type(4))) float f4;
typedef __attribute__((ext_vector_type(8))) short s8;          // 8 bf16 MFMA frag
typedef __attribute__((ext_vector_type(8))) unsigned short us8;
typedef __attribute__((ext_vector_type(2))) unsigned int u2;
typedef __attribute__((ext_vector_type(4))) unsigned int u4i;

// fp32 -> bf16 (RNE), scalar fallback
__device__ __forceinline__ unsigned short f2bf(float f) {
    unsigned int u = __float_as_uint(f);
    u = (u + 0x7FFFu + ((u >> 16) & 1u)) >> 16;
    return (unsigned short)u;
}
// HW packed convert: dst = {bf16(lo), bf16(hi)}  (T12 recipe; no builtin on gfx950)
__device__ __forceinline__ unsigned int cvtpk(float lo, float hi) {
    unsigned int r;
    asm("v_cvt_pk_bf16_f32 %0, %1, %2" : "=v"(r) : "v"(lo), "v"(hi));
    return r;
}
// XOR-swizzled byte offset within a 128B-row LDS tile (T2; verified round 8)
__device__ __forceinline__ int swz128(int row, int colByte) {
    return row * 128 + (colByte ^ ((row & 7) << 4));
}

union s8u4 { s8 s; u4i u; };

// ---------------------------------------------------------------------------
// prepw: 4 blocks. Concat-convert Wq/Wk/Wv -> Wb[320][256] bf16, fb[320] f32.
// ---------------------------------------------------------------------------
__global__ __launch_bounds__(256) void prepw_kernel(
    const float* __restrict__ Wq, const float* __restrict__ bq,
    const float* __restrict__ Wk, const float* __restrict__ bk,
    const float* __restrict__ Wv, const float* __restrict__ bv,
    unsigned short* __restrict__ Wb, float* __restrict__ fb)
{
    const int t = threadIdx.x;
    const int w = blockIdx.x;
    for (int i = 0; i < 80; ++i) {
        const int e = w * 20480 + i * 256 + t;
        const int u = e >> 8, c = e & 255;
        float val = (u < 32) ? Wq[u * 256 + c]
                  : (u < 64) ? Wk[(u - 32) * 256 + c]
                             : Wv[(u - 64) * 256 + c];
        Wb[e] = f2bf(val);
    }
    if (w == 0) {
        for (int u = t; u < MU; u += 256)
            fb[u] = (u < 32) ? bq[u] : (u < 64) ? bk[u - 32] : bv[u - 64];
    }
}

// ---------------------------------------------------------------------------
// projf: fused transpose + MFMA projection.
// grid = b(4) x nbl(128) (32 n each); block 256 = 4 waves.
// Phase 1: stage x[b][all 256 c][32 n] fp32 -> LDS xl[32][260]  (FIXED dims;
//          round-7 bug was xl[32][132] written to col 255).
// Phase 2: lane converts its n-row to 8 bf16 frags via cvt_pk, then wave
//          (nw = w&1: 16 n; uw = w>>1: 10 u-tiles) does 8 MFMA per u-tile.
// q rows are PRE-SCALED by LOG2E (so downstream uses exp2 without a mul).
// Stores qb[n][32], kb[n][32], vtb[c][n] (UNSCALED v; colstats scales it).
// ---------------------------------------------------------------------------
__global__ __launch_bounds__(256) void projf_kernel(
    const float* __restrict__ x, const unsigned short* __restrict__ Wb,
    const float* __restrict__ fb,
    unsigned short* __restrict__ qb, unsigned short* __restrict__ kb,
    unsigned short* __restrict__ vtb)
{
    __shared__ float xl[32][260];

    const int t   = threadIdx.x;
    const int b   = blockIdx.x >> 7;
    const int nbl = blockIdx.x & 127;
    const int n0  = nbl * 32;

    {   // stage: thread (nl = t&7 -> n-quad, c8 = t>>3) reads f4 along n
        const int nl = t & 7;
        const int c8 = t >> 3;
        #pragma unroll
        for (int pass = 0; pass < 8; ++pass) {
            const int c = c8 + pass * 32;
            f4 xv = *reinterpret_cast<const f4*>(x + ((size_t)(b * CC + c)) * NN + n0 + nl * 4);
            #pragma unroll
            for (int j = 0; j < 4; ++j) xl[nl * 4 + j][c] = xv[j];
        }
    }
    __syncthreads();

    const int w    = t >> 6;
    const int l    = t & 63;
    const int l15  = l & 15;
    const int g4   = l >> 4;
    const int nw   = w & 1;
    const int uw   = w >> 1;
    const int nloc = nw * 16 + l15;
    const int n    = n0 + nloc;

    s8 bfr[8];
    #pragma unroll
    for (int kk = 0; kk < 8; ++kk) {
        f4 a  = *reinterpret_cast<const f4*>(&xl[nloc][kk * 32 + g4 * 8]);
        f4 c2 = *reinterpret_cast<const f4*>(&xl[nloc][kk * 32 + g4 * 8 + 4]);
        s8u4 tmp;
        tmp.u = (u4i){ cvtpk(a[0], a[1]), cvtpk(a[2], a[3]),
                       cvtpk(c2[0], c2[1]), cvtpk(c2[2], c2[3]) };
        bfr[kk] = tmp.s;
    }

    const f4 z = {0.f, 0.f, 0.f, 0.f};
    unsigned short* qrow = qb + ((size_t)(b * NN + n)) * CO;
    unsigned short* krow = kb + ((size_t)(b * NN + n)) * CO;

    #pragma unroll
    for (int i = 0; i < 10; ++i) {
        const int u0 = (uw * 10 + i) * 16;
        f4 acc = z;
        #pragma unroll
        for (int kk = 0; kk < 8; ++kk) {
            s8 af = *reinterpret_cast<const s8*>(Wb + (size_t)(u0 + l15) * CC + kk * 32 + g4 * 8);
            acc = __builtin_amdgcn_mfma_f32_16x16x32_bf16(af, bfr[kk], acc, 0, 0, 0);
        }
        f4 bias4 = *reinterpret_cast<const f4*>(fb + u0 + g4 * 4);
        if (u0 < 32) {
            u2 pw = { cvtpk((acc[0] + bias4[0]) * LOG2E, (acc[1] + bias4[1]) * LOG2E),
                      cvtpk((acc[2] + bias4[2]) * LOG2E, (acc[3] + bias4[3]) * LOG2E) };
            *reinterpret_cast<u2*>(qrow + u0 + g4 * 4) = pw;
        } else if (u0 < 64) {
            u2 pw = { cvtpk(acc[0] + bias4[0], acc[1] + bias4[1]),
                      cvtpk(acc[2] + bias4[2], acc[3] + bias4[3]) };
            *reinterpret_cast<u2*>(krow + (u0 - 32) + g4 * 4) = pw;
        } else {
            const int cbase = u0 - 64 + g4 * 4;
            #pragma unroll
            for (int r = 0; r < 4; ++r)
                vtb[((size_t)(b * CC + cbase + r)) * NN + n] = f2bf(acc[r] + bias4[r]);
        }
    }
}

// ---------------------------------------------------------------------------
// colstats + vscale: per block (b, mb: 32 m-columns):
//   civ[m] = 1 / sum_n exp2(S[n,m])   (q pre-scaled by log2e => exp2 == exp);
//   then scale vtb[:, m-slice] by civ in place (disjoint per block, rewritten
//   by projf every launch => deterministic).
// grid = b(4) x mb(128); block 256 (waves split m-half x n-half).
// ---------------------------------------------------------------------------
__global__ __launch_bounds__(256) void colstats_kernel(
    const unsigned short* __restrict__ qb, const unsigned short* __restrict__ kb,
    unsigned short* __restrict__ vtb)
{
    __shared__ float red[4][16];
    __shared__ float civl[32];

    const int t   = threadIdx.x;
    const int b   = blockIdx.x >> 7;
    const int mb  = blockIdx.x & 127;
    const int l   = t & 63;
    const int w   = t >> 6;
    const int l15 = l & 15;
    const int g4  = l >> 4;
    const int m   = mb * 32 + (w & 1) * 16 + l15;
    const int nh  = w >> 1;

    const unsigned short* qbB = qb + (size_t)b * NN * CO;
    s8 kfrag = *reinterpret_cast<const s8*>(kb + ((size_t)b * NN + m) * CO + g4 * 8);

    const f4 z = {0.f, 0.f, 0.f, 0.f};
    float ssum = 0.f;

    const int nbeg = nh * 2048, nend = nbeg + 2048;
    for (int n0 = nbeg; n0 < nend; n0 += 32) {
        s8 a0 = *reinterpret_cast<const s8*>(qbB + (size_t)(n0 + l15) * CO + g4 * 8);
        s8 a1 = *reinterpret_cast<const s8*>(qbB + (size_t)(n0 + 16 + l15) * CO + g4 * 8);
        f4 d0 = __builtin_amdgcn_mfma_f32_16x16x32_bf16(a0, kfrag, z, 0, 0, 0);
        f4 d1 = __builtin_amdgcn_mfma_f32_16x16x32_bf16(a1, kfrag, z, 0, 0, 0);
        #pragma unroll
        for (int r = 0; r < 4; ++r) ssum += exp2f(d0[r]) + exp2f(d1[r]);
    }

    ssum += __shfl_xor(ssum, 16);
    ssum += __shfl_xor(ssum, 32);
    if (l < 16) red[w][l15] = ssum;
    __syncthreads();
    if (w < 2 && l < 16)
        civl[w * 16 + l15] = 1.0f / (red[w][l15] + red[w + 2][l15]);
    __syncthreads();

    // scale vtb columns m = mb*32..+32 for c-row = t (in place)
    unsigned short* vp = vtb + ((size_t)(b * CC + t)) * NN + mb * 32;
    #pragma unroll
    for (int i = 0; i < 4; ++i) {
        us8 vv = *reinterpret_cast<const us8*>(vp + i * 8);
        u4i o;
        #pragma unroll
        for (int e2 = 0; e2 < 4; ++e2) {
            float f0 = __uint_as_float((unsigned int)vv[2 * e2]     << 16) * civl[i * 8 + 2 * e2];
            float f1 = __uint_as_float((unsigned int)vv[2 * e2 + 1] << 16) * civl[i * 8 + 2 * e2 + 1];
            o[e2] = cvtpk(f0, f1);
        }
        *reinterpret_cast<u4i*>(vp + i * 8) = o;
    }
}

// ---------------------------------------------------------------------------
// attn: out[n,c] = sum_m exp2(S[n,m]) * v'[m,c]   (v' pre-scaled by cinv,
// q pre-scaled by log2e).  Round-8 verified structure: 64n x 128c tile,
// grid 512, swapped S-MFMA, XOR-swizzled double-buffered LDS, setprio.
// Stage now: 4 MFMA + 16 exp2 + 8 cvt_pk per thread (was ~110 VALU).
// ---------------------------------------------------------------------------
__global__ __launch_bounds__(256) void attn_kernel(
    const unsigned short* __restrict__ qb, const unsigned short* __restrict__ kb,
    const unsigned short* __restrict__ vtb, float* __restrict__ out)
{
    __shared__ __align__(16) char plds[2][64 * 128];    // P tile  [n][m] bf16, swizzled
    __shared__ __align__(16) char vlds[2][128 * 128];   // vT tile [c][m] bf16, swizzled

    const int t    = threadIdx.x;
    const int bid  = blockIdx.x;
    const int cblk = bid & 1;
    const int nblk = (bid >> 1) & 63;
    const int b    = bid >> 7;
    const int n0   = nblk * 64;
    const int c0   = cblk * 128;
    const int l    = t & 63;
    const int w    = t >> 6;
    const int l15  = l & 15;
    const int g4   = l >> 4;
    const int wr   = w >> 1;       // PV n-half
    const int wc   = w & 1;        // PV c-half

    const unsigned short* qbB = qb  + (size_t)b * NN * CO;
    const unsigned short* kbB = kb  + (size_t)b * NN * CO;
    const unsigned short* vtB = vtb + (size_t)b * CC * NN;

    // wave's 16 S-rows (B-operand of swapped MFMA)
    s8 qfrag = *reinterpret_cast<const s8*>(qbB + (size_t)(n0 + w * 16 + l15) * CO + g4 * 8);

    s8 kreg[4];
    s8 vs[4];
    const int vrow  = t >> 1;          // c-local row staged by this thread
    const int vhalf = (t & 1) * 64;    // byte offset of m-half in LDS row

    auto loadnext = [&](int mP) {
        #pragma unroll
        for (int j = 0; j < 4; ++j)
            kreg[j] = *reinterpret_cast<const s8*>(kbB + (size_t)(mP + j * 16 + l15) * CO + g4 * 8);
        const unsigned short* vsrc = vtB + (size_t)(c0 + vrow) * NN + mP + (t & 1) * 32;
        #pragma unroll
        for (int j = 0; j < 4; ++j)
            vs[j] = *reinterpret_cast<const s8*>(vsrc + j * 8);
    };

    const f4 z = {0.f, 0.f, 0.f, 0.f};

    auto stage = [&](int buf) {
        // swapped S: d = mfma(K_rows(m), Q_rows(n)):
        //   lane (l15,g4): n = w*16+l15, m = j*16 + g4*4 + r
        #pragma unroll
        for (int j = 0; j < 4; ++j) {
            f4 d = __builtin_amdgcn_mfma_f32_16x16x32_bf16(kreg[j], qfrag, z, 0, 0, 0);
            u2 pw = { cvtpk(exp2f(d[0]), exp2f(d[1])),
                      cvtpk(exp2f(d[2]), exp2f(d[3])) };
            *reinterpret_cast<u2*>(plds[buf] + swz128(w * 16 + l15, j * 32 + g4 * 8)) = pw;
        }
        #pragma unroll
        for (int j = 0; j < 4; ++j)
            *reinterpret_cast<s8*>(vlds[buf] + swz128(vrow, vhalf + j * 16)) = vs[j];
    };

    f4 acc[2][4];
    #pragma unroll
    for (int a = 0; a < 2; ++a)
        #pragma unroll
        for (int c = 0; c < 4; ++c) acc[a][c] = z;

    loadnext(0);
    stage(0);
    loadnext(64);
    __syncthreads();

    for (int i = 0; i < 64; ++i) {
        const int cur = i & 1;
        if (i < 63) {
            stage(cur ^ 1);
            if (i < 62) loadnext((i + 2) * 64);
        }
        #pragma unroll
        for (int ksl = 0; ksl < 2; ++ksl) {
            s8 pa[2], vb[4];
            #pragma unroll
            for (int a = 0; a < 2; ++a)
                pa[a] = *reinterpret_cast<const s8*>(
                    plds[cur] + swz128(wr * 32 + a * 16 + l15, ksl * 64 + g4 * 16));
            #pragma unroll
            for (int c = 0; c < 4; ++c)
                vb[c] = *reinterpret_cast<const s8*>(
                    vlds[cur] + swz128(wc * 64 + c * 16 + l15, ksl * 64 + g4 * 16));
            __builtin_amdgcn_s_setprio(1);
            #pragma unroll
            for (int a = 0; a < 2; ++a)
                #pragma unroll
                for (int c = 0; c < 4; ++c)
                    acc[a][c] = __builtin_amdgcn_mfma_f32_16x16x32_bf16(pa[a], vb[c], acc[a][c], 0, 0, 0);
            __builtin_amdgcn_s_setprio(0);
        }
        __syncthreads();
    }

    // D layout: col = lane&15 (c), row = g4*4 + r (n)
    #pragma unroll
    for (int a = 0; a < 2; ++a) {
        const int row = n0 + wr * 32 + a * 16 + g4 * 4;
        #pragma unroll
        for (int c = 0; c < 4; ++c) {
            const int col = c0 + wc * 64 + c * 16 + l15;
            #pragma unroll
            for (int r = 0; r < 4; ++r)
                out[((size_t)(b * NN + row + r)) * CC + col] = acc[a][c][r];
        }
    }
}

extern "C" void kernel_launch(void* const* d_in, const int* in_sizes, int n_in,
                              void* d_out, int out_size, void* d_ws, size_t ws_size,
                              hipStream_t stream)
{
    const float* x  = (const float*)d_in[0];
    const float* Wq = (const float*)d_in[1];
    const float* bq = (const float*)d_in[2];
    const float* Wk = (const float*)d_in[3];
    const float* bk = (const float*)d_in[4];
    const float* Wv = (const float*)d_in[5];
    const float* bv = (const float*)d_in[6];
    float* out = (float*)d_out;

    // ws layout: qb(1MB) | kb(1MB) | vtb(8MB) | Wb(160KB) | fb(1.25KB)
    unsigned short* qb  = (unsigned short*)d_ws;
    unsigned short* kb  = qb + (size_t)NB * NN * CO;
    unsigned short* vtb = kb + (size_t)NB * NN * CO;
    unsigned short* Wb  = vtb + (size_t)NB * CC * NN;
    float*          fb  = (float*)(Wb + (size_t)MU * CC);

    prepw_kernel<<<dim3(4), dim3(256), 0, stream>>>(Wq, bq, Wk, bk, Wv, bv, Wb, fb);
    projf_kernel<<<dim3(512), dim3(256), 0, stream>>>(x, Wb, fb, qb, kb, vtb);
    colstats_kernel<<<dim3(512), dim3(256), 0, stream>>>(qb, kb, vtb);
    attn_kernel<<<dim3(512), dim3(256), 0, stream>>>(qb, kb, vtb, out);
}

// Round 11
// 131.694 us; speedup vs baseline: 7.7093x; 1.2079x over previous
//
#include <hip/hip_runtime.h>
#include <math.h>

#define NB 4
#define CC 256
#define CO 32
#define NN 4096
#define MU 320   // concat projection rows: 32 q + 32 k + 256 v
#define LOG2E 1.44269504088896f

typedef __attribute__((ext_vector_type(4))) float f4;
typedef __attribute__((ext_vector_type(8))) short s8;          // 8 bf16 MFMA frag
typedef __attribute__((ext_vector_type(8))) unsigned short us8;
typedef __attribute__((ext_vector_type(2))) unsigned int u2;
typedef __attribute__((ext_vector_type(4))) unsigned int u4i;

// fp32 -> bf16 (RNE), scalar fallback
__device__ __forceinline__ unsigned short f2bf(float f) {
    unsigned int u = __float_as_uint(f);
    u = (u + 0x7FFFu + ((u >> 16) & 1u)) >> 16;
    return (unsigned short)u;
}
// HW packed convert: dst = {bf16(lo), bf16(hi)}
__device__ __forceinline__ unsigned int cvtpk(float lo, float hi) {
    unsigned int r;
    asm("v_cvt_pk_bf16_f32 %0, %1, %2" : "=v"(r) : "v"(lo), "v"(hi));
    return r;
}
// XOR-swizzled byte offset within a 128B-row LDS tile (verified round 8)
__device__ __forceinline__ int swz128(int row, int colByte) {
    return row * 128 + (colByte ^ ((row & 7) << 4));
}

union s8u4 { s8 s; u4i u; };

// ---------------------------------------------------------------------------
// prepw: grid 80 (was 4 -- latency-bound). Wb[320][256] bf16, fb[320] f32.
// ---------------------------------------------------------------------------
__global__ __launch_bounds__(256) void prepw_kernel(
    const float* __restrict__ Wq, const float* __restrict__ bq,
    const float* __restrict__ Wk, const float* __restrict__ bk,
    const float* __restrict__ Wv, const float* __restrict__ bv,
    unsigned short* __restrict__ Wb, float* __restrict__ fb)
{
    const int t = threadIdx.x;
    #pragma unroll
    for (int i = 0; i < 4; ++i) {
        const int e = blockIdx.x * 1024 + i * 256 + t;
        const int u = e >> 8, c = e & 255;
        float val = (u < 32) ? Wq[u * 256 + c]
                  : (u < 64) ? Wk[(u - 32) * 256 + c]
                             : Wv[(u - 64) * 256 + c];
        Wb[e] = f2bf(val);
    }
    if (blockIdx.x == 0) {
        for (int u = t; u < MU; u += 256)
            fb[u] = (u < 32) ? bq[u] : (u < 64) ? bk[u - 32] : bv[u - 64];
    }
}

// ---------------------------------------------------------------------------
// projf: fused transpose + MFMA projection (unchanged from round-10 passing).
// q pre-scaled by LOG2E; vtb unscaled (colstats scales it).
// ---------------------------------------------------------------------------
__global__ __launch_bounds__(256) void projf_kernel(
    const float* __restrict__ x, const unsigned short* __restrict__ Wb,
    const float* __restrict__ fb,
    unsigned short* __restrict__ qb, unsigned short* __restrict__ kb,
    unsigned short* __restrict__ vtb)
{
    __shared__ float xl[32][260];

    const int t   = threadIdx.x;
    const int b   = blockIdx.x >> 7;
    const int nbl = blockIdx.x & 127;
    const int n0  = nbl * 32;

    {
        const int nl = t & 7;
        const int c8 = t >> 3;
        #pragma unroll
        for (int pass = 0; pass < 8; ++pass) {
            const int c = c8 + pass * 32;
            f4 xv = *reinterpret_cast<const f4*>(x + ((size_t)(b * CC + c)) * NN + n0 + nl * 4);
            #pragma unroll
            for (int j = 0; j < 4; ++j) xl[nl * 4 + j][c] = xv[j];
        }
    }
    __syncthreads();

    const int w    = t >> 6;
    const int l    = t & 63;
    const int l15  = l & 15;
    const int g4   = l >> 4;
    const int nw   = w & 1;
    const int uw   = w >> 1;
    const int nloc = nw * 16 + l15;
    const int n    = n0 + nloc;

    s8 bfr[8];
    #pragma unroll
    for (int kk = 0; kk < 8; ++kk) {
        f4 a  = *reinterpret_cast<const f4*>(&xl[nloc][kk * 32 + g4 * 8]);
        f4 c2 = *reinterpret_cast<const f4*>(&xl[nloc][kk * 32 + g4 * 8 + 4]);
        s8u4 tmp;
        tmp.u = (u4i){ cvtpk(a[0], a[1]), cvtpk(a[2], a[3]),
                       cvtpk(c2[0], c2[1]), cvtpk(c2[2], c2[3]) };
        bfr[kk] = tmp.s;
    }

    const f4 z = {0.f, 0.f, 0.f, 0.f};
    unsigned short* qrow = qb + ((size_t)(b * NN + n)) * CO;
    unsigned short* krow = kb + ((size_t)(b * NN + n)) * CO;

    #pragma unroll
    for (int i = 0; i < 10; ++i) {
        const int u0 = (uw * 10 + i) * 16;
        f4 acc = z;
        #pragma unroll
        for (int kk = 0; kk < 8; ++kk) {
            s8 af = *reinterpret_cast<const s8*>(Wb + (size_t)(u0 + l15) * CC + kk * 32 + g4 * 8);
            acc = __builtin_amdgcn_mfma_f32_16x16x32_bf16(af, bfr[kk], acc, 0, 0, 0);
        }
        f4 bias4 = *reinterpret_cast<const f4*>(fb + u0 + g4 * 4);
        if (u0 < 32) {
            u2 pw = { cvtpk((acc[0] + bias4[0]) * LOG2E, (acc[1] + bias4[1]) * LOG2E),
                      cvtpk((acc[2] + bias4[2]) * LOG2E, (acc[3] + bias4[3]) * LOG2E) };
            *reinterpret_cast<u2*>(qrow + u0 + g4 * 4) = pw;
        } else if (u0 < 64) {
            u2 pw = { cvtpk(acc[0] + bias4[0], acc[1] + bias4[1]),
                      cvtpk(acc[2] + bias4[2], acc[3] + bias4[3]) };
            *reinterpret_cast<u2*>(krow + (u0 - 32) + g4 * 4) = pw;
        } else {
            const int cbase = u0 - 64 + g4 * 4;
            #pragma unroll
            for (int r = 0; r < 4; ++r)
                vtb[((size_t)(b * CC + cbase + r)) * NN + n] = f2bf(acc[r] + bias4[r]);
        }
    }
}

// ---------------------------------------------------------------------------
// colstats + vscale: grid 1024 (was 512). Block = (b, mb: 16 m-columns);
// 4 waves each sum an n-quarter; combine; scale vtb[:, m-slice] in place.
// ---------------------------------------------------------------------------
__global__ __launch_bounds__(256) void colstats_kernel(
    const unsigned short* __restrict__ qb, const unsigned short* __restrict__ kb,
    unsigned short* __restrict__ vtb)
{
    __shared__ float red[4][16];
    __shared__ float civl[16];

    const int t   = threadIdx.x;
    const int b   = blockIdx.x >> 8;
    const int mb  = blockIdx.x & 255;
    const int l   = t & 63;
    const int w   = t >> 6;
    const int l15 = l & 15;
    const int g4  = l >> 4;
    const int m   = mb * 16 + l15;

    const unsigned short* qbB = qb + (size_t)b * NN * CO;
    s8 kfrag = *reinterpret_cast<const s8*>(kb + ((size_t)b * NN + m) * CO + g4 * 8);

    const f4 z = {0.f, 0.f, 0.f, 0.f};
    float ssum = 0.f;

    const int nbeg = w * 1024, nend = nbeg + 1024;
    for (int n0 = nbeg; n0 < nend; n0 += 32) {
        s8 a0 = *reinterpret_cast<const s8*>(qbB + (size_t)(n0 + l15) * CO + g4 * 8);
        s8 a1 = *reinterpret_cast<const s8*>(qbB + (size_t)(n0 + 16 + l15) * CO + g4 * 8);
        f4 d0 = __builtin_amdgcn_mfma_f32_16x16x32_bf16(a0, kfrag, z, 0, 0, 0);
        f4 d1 = __builtin_amdgcn_mfma_f32_16x16x32_bf16(a1, kfrag, z, 0, 0, 0);
        #pragma unroll
        for (int r = 0; r < 4; ++r) ssum += exp2f(d0[r]) + exp2f(d1[r]);
    }

    ssum += __shfl_xor(ssum, 16);
    ssum += __shfl_xor(ssum, 32);
    if (l < 16) red[w][l15] = ssum;
    __syncthreads();
    if (w == 0 && l < 16)
        civl[l15] = 1.0f / (red[0][l15] + red[1][l15] + red[2][l15] + red[3][l15]);
    __syncthreads();

    // scale vtb columns m = mb*16..+16 for c-row = t (in place; disjoint per block)
    unsigned short* vp = vtb + ((size_t)(b * CC + t)) * NN + mb * 16;
    #pragma unroll
    for (int i = 0; i < 2; ++i) {
        us8 vv = *reinterpret_cast<const us8*>(vp + i * 8);
        u4i o;
        #pragma unroll
        for (int e2 = 0; e2 < 4; ++e2) {
            float f0 = __uint_as_float((unsigned int)vv[2 * e2]     << 16) * civl[i * 8 + 2 * e2];
            float f1 = __uint_as_float((unsigned int)vv[2 * e2 + 1] << 16) * civl[i * 8 + 2 * e2 + 1];
            o[e2] = cvtpk(f0, f1);
        }
        *reinterpret_cast<u4i*>(vp + i * 8) = o;
    }
}

// ---------------------------------------------------------------------------
// attn: out[n,c] = sum_m exp2(S[n,m]) * v'[m,c]  (v' pre-scaled, q pre-log2e).
// NOW 512 threads / 8 waves per block (was 4): same 64n x 128c tile, same
// swizzled dbuf LDS (48 KB), 16 waves/CU for latency hiding.
//   S: wave (g = w>>1 owns 16 n-rows, p = w&1 owns j-pair) -> 2 S-MFMA,
//      8 exp2, 4 cvt_pk, 2 b64 P-writes.
//   V: 512 threads stage 2 b128 each.
//   PV: wave quadrant 32n x 32c (wrn = w>>2, wcq = w&3): 8 reads, 8 MFMA.
// ---------------------------------------------------------------------------
__global__ __launch_bounds__(512) void attn_kernel(
    const unsigned short* __restrict__ qb, const unsigned short* __restrict__ kb,
    const unsigned short* __restrict__ vtb, float* __restrict__ out)
{
    __shared__ __align__(16) char plds[2][64 * 128];    // P tile  [n][m] bf16, swizzled
    __shared__ __align__(16) char vlds[2][128 * 128];   // vT tile [c][m] bf16, swizzled

    const int t    = threadIdx.x;
    const int bid  = blockIdx.x;
    const int cblk = bid & 1;
    const int nblk = (bid >> 1) & 63;
    const int b    = bid >> 7;
    const int n0   = nblk * 64;
    const int c0   = cblk * 128;
    const int l    = t & 63;
    const int w    = t >> 6;        // 0..7
    const int l15  = l & 15;
    const int g4   = l >> 4;
    const int g    = w >> 1;        // S n-group (16 rows)
    const int p    = w & 1;         // S j-pair
    const int wrn  = w >> 2;        // PV n-half
    const int wcq  = w & 3;         // PV c-quarter

    const unsigned short* qbB = qb  + (size_t)b * NN * CO;
    const unsigned short* kbB = kb  + (size_t)b * NN * CO;
    const unsigned short* vtB = vtb + (size_t)b * CC * NN;

    // wave's 16 S-rows (B-operand of swapped MFMA)
    s8 qfrag = *reinterpret_cast<const s8*>(qbB + (size_t)(n0 + g * 16 + l15) * CO + g4 * 8);

    s8 kreg[2];
    s8 vs[2];
    const int vrow = t >> 2;           // c-local row staged by this thread (0..127)
    const int q4   = t & 3;            // m-quarter (16 m = 32B)

    auto loadnext = [&](int mP) {
        #pragma unroll
        for (int j2 = 0; j2 < 2; ++j2)
            kreg[j2] = *reinterpret_cast<const s8*>(kbB + (size_t)(mP + (2 * p + j2) * 16 + l15) * CO + g4 * 8);
        const unsigned short* vsrc = vtB + (size_t)(c0 + vrow) * NN + mP + q4 * 16;
        vs[0] = *reinterpret_cast<const s8*>(vsrc);
        vs[1] = *reinterpret_cast<const s8*>(vsrc + 8);
    };

    const f4 z = {0.f, 0.f, 0.f, 0.f};

    auto stage = [&](int buf) {
        // swapped S: d = mfma(K_rows(m), Q_rows(n)):
        //   lane (l15,g4): n = g*16+l15, m = (2p+j2)*16 + g4*4 + r
        #pragma unroll
        for (int j2 = 0; j2 < 2; ++j2) {
            f4 d = __builtin_amdgcn_mfma_f32_16x16x32_bf16(kreg[j2], qfrag, z, 0, 0, 0);
            u2 pw = { cvtpk(exp2f(d[0]), exp2f(d[1])),
                      cvtpk(exp2f(d[2]), exp2f(d[3])) };
            *reinterpret_cast<u2*>(plds[buf] + swz128(g * 16 + l15, (2 * p + j2) * 32 + g4 * 8)) = pw;
        }
        *reinterpret_cast<s8*>(vlds[buf] + swz128(vrow, q4 * 32))      = vs[0];
        *reinterpret_cast<s8*>(vlds[buf] + swz128(vrow, q4 * 32 + 16)) = vs[1];
    };

    f4 acc[2][2];
    #pragma unroll
    for (int a = 0; a < 2; ++a)
        #pragma unroll
        for (int c = 0; c < 2; ++c) acc[a][c] = z;

    loadnext(0);
    stage(0);
    loadnext(64);
    __syncthreads();

    for (int i = 0; i < 64; ++i) {
        const int cur = i & 1;
        if (i < 63) {
            stage(cur ^ 1);
            if (i < 62) loadnext((i + 2) * 64);
        }
        #pragma unroll
        for (int ksl = 0; ksl < 2; ++ksl) {
            s8 pa[2], vb[2];
            #pragma unroll
            for (int a = 0; a < 2; ++a)
                pa[a] = *reinterpret_cast<const s8*>(
                    plds[cur] + swz128(wrn * 32 + a * 16 + l15, ksl * 64 + g4 * 16));
            #pragma unroll
            for (int c = 0; c < 2; ++c)
                vb[c] = *reinterpret_cast<const s8*>(
                    vlds[cur] + swz128(wcq * 32 + c * 16 + l15, ksl * 64 + g4 * 16));
            __builtin_amdgcn_s_setprio(1);
            #pragma unroll
            for (int a = 0; a < 2; ++a)
                #pragma unroll
                for (int c = 0; c < 2; ++c)
                    acc[a][c] = __builtin_amdgcn_mfma_f32_16x16x32_bf16(pa[a], vb[c], acc[a][c], 0, 0, 0);
            __builtin_amdgcn_s_setprio(0);
        }
        __syncthreads();
    }

    // D layout: col = lane&15 (c), row = g4*4 + r (n)
    #pragma unroll
    for (int a = 0; a < 2; ++a) {
        const int row = n0 + wrn * 32 + a * 16 + g4 * 4;
        #pragma unroll
        for (int c = 0; c < 2; ++c) {
            const int col = c0 + wcq * 32 + c * 16 + l15;
            #pragma unroll
            for (int r = 0; r < 4; ++r)
                out[((size_t)(b * NN + row + r)) * CC + col] = acc[a][c][r];
        }
    }
}

extern "C" void kernel_launch(void* const* d_in, const int* in_sizes, int n_in,
                              void* d_out, int out_size, void* d_ws, size_t ws_size,
                              hipStream_t stream)
{
    const float* x  = (const float*)d_in[0];
    const float* Wq = (const float*)d_in[1];
    const float* bq = (const float*)d_in[2];
    const float* Wk = (const float*)d_in[3];
    const float* bk = (const float*)d_in[4];
    const float* Wv = (const float*)d_in[5];
    const float* bv = (const float*)d_in[6];
    float* out = (float*)d_out;

    // ws layout: qb(1MB) | kb(1MB) | vtb(8MB) | Wb(160KB) | fb(1.25KB)
    unsigned short* qb  = (unsigned short*)d_ws;
    unsigned short* kb  = qb + (size_t)NB * NN * CO;
    unsigned short* vtb = kb + (size_t)NB * NN * CO;
    unsigned short* Wb  = vtb + (size_t)NB * CC * NN;
    float*          fb  = (float*)(Wb + (size_t)MU * CC);

    prepw_kernel<<<dim3(80), dim3(256), 0, stream>>>(Wq, bq, Wk, bk, Wv, bv, Wb, fb);
    projf_kernel<<<dim3(512), dim3(256), 0, stream>>>(x, Wb, fb, qb, kb, vtb);
    colstats_kernel<<<dim3(1024), dim3(256), 0, stream>>>(qb, kb, vtb);
    attn_kernel<<<dim3(512), dim3(512), 0, stream>>>(qb, kb, vtb, out);
}